// Round 1
// baseline (2390.038 us; speedup 1.0000x reference)
//
#include <hip/hip_runtime.h>
#include <hip/hip_bf16.h>

#define B_   4096
#define T_   200
#define KA   16

// ---- workspace layout (float offsets) ----
#define OFF_W1  0
#define OFF_QP  (OFF_W1  + B_*T_)
#define OFF_UI1 (OFF_QP  + B_*64)
#define OFF_UI2 (OFF_UI1 + B_*64)
#define OFF_HF  (OFF_UI2 + B_*64)
#define OFF_CL  (OFF_HF  + B_*64)

__device__ __forceinline__ float sigmoidf_(float x) {
  return 1.f / (1.f + __expf(-x));
}
__device__ __forceinline__ float tanhf_(float x) {
  x = fminf(fmaxf(x, -15.f), 15.f);
  float e = __expf(2.f * x);
  return (e - 1.f) / (e + 1.f);
}

// ============================================================
// K1: activation unit over history: w1[b,t], qp[b,64], ui_l1[b,64]
//   hid = relu(k@Wk + qp),  Wk = W1[0:64]+W1[128:192], Wkq = W1[192:256]
//   qp  = b1 + item@(W1[64:128]-W1[128:192])
// ============================================================
__global__ __launch_bounds__(256) void k_act1(
    const int* __restrict__ item_id, const int* __restrict__ hist_ids,
    const float* __restrict__ emb, const float* __restrict__ auW1,
    const float* __restrict__ aub1, const float* __restrict__ auW2,
    const float* __restrict__ aub2,
    float* __restrict__ w1_out, float* __restrict__ qp_out,
    float* __restrict__ ui1_out)
{
  __shared__ float sWk[64*64], sWkq[64*64];
  __shared__ float sQp[64], sItem[64], sW2[64];
  __shared__ float sUi[4][64];
  const int b = blockIdx.x;
  const int tid = threadIdx.x;

  for (int idx = tid; idx < 4096; idx += 256) {
    float a = auW1[idx];            // rows 0:64  (keys)
    float c = auW1[2*4096 + idx];   // rows 128:192 (k - q)
    float d = auW1[3*4096 + idx];   // rows 192:256 (k * q)
    sWk[idx]  = a + c;
    sWkq[idx] = d;
  }
  if (tid < 64) {
    sW2[tid]   = auW2[tid];
    sItem[tid] = emb[(size_t)item_id[b]*64 + tid];
  }
  __syncthreads();
  if (tid < 64) {
    float acc = aub1[tid];
    for (int i = 0; i < 64; ++i) {
      float wq = auW1[(64+i)*64 + tid] - auW1[(128+i)*64 + tid];
      acc += sItem[i] * wq;
    }
    sQp[tid] = acc;
    qp_out[(size_t)b*64 + tid] = acc;
  }
  __syncthreads();

  const int wave = tid >> 6, lane = tid & 63;
  const float q   = sItem[lane];
  const float b2v = aub2[0];
  float accui = 0.f;
  for (int t = wave; t < T_; t += 4) {
    int row  = hist_ids[(size_t)b*T_ + t];
    float kv = emb[(size_t)row*64 + lane];
    float kq = kv * q;
    float acc = 0.f;
    #pragma unroll
    for (int i = 0; i < 64; ++i) {
      float ki  = __shfl(kv, i);
      float kqi = __shfl(kq, i);
      acc += ki * sWk[i*64 + lane] + kqi * sWkq[i*64 + lane];
    }
    float hid = fmaxf(acc + sQp[lane], 0.f);
    float w = hid * sW2[lane];
    #pragma unroll
    for (int off = 32; off > 0; off >>= 1) w += __shfl_xor(w, off);
    w += b2v;
    if (lane == 0) w1_out[(size_t)b*T_ + t] = w;
    accui += w * kv;
  }
  sUi[wave][lane] = accui;
  __syncthreads();
  if (tid < 64) {
    ui1_out[(size_t)b*64 + tid] =
        sUi[0][tid] + sUi[1][tid] + sUi[2][tid] + sUi[3][tid];
  }
}

// ============================================================
// K2: per-attribute masked softmax over t + cluster[b,k,64]
// ============================================================
__global__ __launch_bounds__(256) void k_cluster(
    const int* __restrict__ hist_ids, const int* __restrict__ attrs,
    const float* __restrict__ emb, const float* __restrict__ w1_in,
    float* __restrict__ cluster_out)
{
  __shared__ float sW1[T_];
  __shared__ int sAttr[T_], sIds[T_];
  const int b = blockIdx.x;
  const int tid = threadIdx.x;
  if (tid < T_) {
    sW1[tid]   = w1_in[(size_t)b*T_ + tid];
    sAttr[tid] = attrs[(size_t)b*T_ + tid];
    sIds[tid]  = hist_ids[(size_t)b*T_ + tid];
  }
  __syncthreads();
  const int wave = tid >> 6, lane = tid & 63;
  for (int k = wave; k < KA; k += 4) {
    float m = -1e9f;
    for (int tt = 0; tt < 4; ++tt) {
      int t = tt*64 + lane;
      if (t < T_ && sAttr[t] == k) m = fmaxf(m, sW1[t]);
    }
    #pragma unroll
    for (int off = 32; off > 0; off >>= 1) m = fmaxf(m, __shfl_xor(m, off));
    float e = 0.f;
    for (int tt = 0; tt < 4; ++tt) {
      int t = tt*64 + lane;
      if (t < T_ && sAttr[t] == k) e += expf(sW1[t] - m);
    }
    #pragma unroll
    for (int off = 32; off > 0; off >>= 1) e += __shfl_xor(e, off);
    float cj = 0.f;
    if (e > 0.f) {
      float inv = 1.f / e;
      for (int t = 0; t < T_; ++t) {
        if (sAttr[t] == k) {   // wave-uniform branch
          float p = expf(sW1[t] - m) * inv;
          cj += p * emb[(size_t)sIds[t]*64 + lane];
        }
      }
    }
    cluster_out[(size_t)b*(KA*64) + k*64 + lane] = cj;
  }
}

// ============================================================
// K3: GRU over history, 16 batch rows/block, weights in registers.
//   thread = (j in 0..191, sub in 0..1 [i-half], g in 0..1 [row-half])
// ============================================================
#define GRU_ROWS 16
#define GRU_THREADS 768

__global__ __launch_bounds__(GRU_THREADS) void k_gru(
    const int* __restrict__ hist_ids, const float* __restrict__ emb,
    const float* __restrict__ Wx, const float* __restrict__ Wh,
    const float* __restrict__ gb, float* __restrict__ hfin_out)
{
  __shared__ __align__(16) float sX[GRU_ROWS][64];
  __shared__ __align__(16) float sH[GRU_ROWS][64];
  __shared__ float sXpA[GRU_ROWS][192], sXpB[GRU_ROWS][192];
  __shared__ float sGhA[GRU_ROWS][192], sGhB[GRU_ROWS][192];

  const int tid = threadIdx.x;
  const int b0  = blockIdx.x * GRU_ROWS;
  const int j   = tid % 192;
  const int sg  = tid / 192;     // 0..3, uniform within a wave
  const int sub = sg & 1;        // which i-half
  const int g   = sg >> 1;       // which row-half (8 rows each)

  // register weights: half of column j of Wx and Wh
  float rwx[32], rwh[32];
  #pragma unroll
  for (int i = 0; i < 32; ++i) {
    rwx[i] = Wx[(size_t)(sub*32 + i)*192 + j];
    rwh[i] = Wh[(size_t)(sub*32 + i)*192 + j];
  }
  const float bj = gb[j];

  for (int idx = tid; idx < GRU_ROWS*64; idx += GRU_THREADS)
    ((float*)sH)[idx] = 0.f;
  __syncthreads();

  // prefetch x(t=0)
  float xa, xb;
  {
    int r1 = hist_ids[(size_t)(b0 + (tid >> 6))*T_ + 0];
    xa = emb[(size_t)r1*64 + (tid & 63)];
    xb = 0.f;
    if (tid < 256) {
      int idx2 = 768 + tid;
      int r2 = hist_ids[(size_t)(b0 + (idx2 >> 6))*T_ + 0];
      xb = emb[(size_t)r2*64 + (idx2 & 63)];
    }
  }

  float (*outXp)[192] = sub ? sXpB : sXpA;
  float (*outGh)[192] = sub ? sGhB : sGhA;

  for (int t = 0; t < T_; ++t) {
    ((float*)sX)[tid] = xa;
    if (tid < 256) ((float*)sX)[768 + tid] = xb;
    __syncthreads();   // sX(t) ready, sH(t) ready

    if (t + 1 < T_) {  // prefetch x(t+1), hidden under compute
      int r1 = hist_ids[(size_t)(b0 + (tid >> 6))*T_ + (t+1)];
      xa = emb[(size_t)r1*64 + (tid & 63)];
      if (tid < 256) {
        int idx2 = 768 + tid;
        int r2 = hist_ids[(size_t)(b0 + (idx2 >> 6))*T_ + (t+1)];
        xb = emb[(size_t)r2*64 + (idx2 & 63)];
      }
    }

    float ax[8], ah[8];
    #pragma unroll
    for (int rr = 0; rr < 8; ++rr) { ax[rr] = sub ? 0.f : bj; ah[rr] = 0.f; }

    const float4* x4 = (const float4*)sX;
    const float4* h4 = (const float4*)sH;
    #pragma unroll
    for (int i4 = 0; i4 < 8; ++i4) {
      const int f4 = sub*8 + i4;  // float4 index within row
      #pragma unroll
      for (int rr = 0; rr < 8; ++rr) {
        const int r = g*8 + rr;
        float4 xv = x4[r*16 + f4];
        float4 hv = h4[r*16 + f4];
        ax[rr] += xv.x*rwx[i4*4+0] + xv.y*rwx[i4*4+1]
                + xv.z*rwx[i4*4+2] + xv.w*rwx[i4*4+3];
        ah[rr] += hv.x*rwh[i4*4+0] + hv.y*rwh[i4*4+1]
                + hv.z*rwh[i4*4+2] + hv.w*rwh[i4*4+3];
      }
    }
    #pragma unroll
    for (int rr = 0; rr < 8; ++rr) {
      const int r = g*8 + rr;
      outXp[r][j] = ax[rr];
      outGh[r][j] = ah[rr];
    }
    __syncthreads();   // partials ready

    for (int idx = tid; idx < GRU_ROWS*64; idx += GRU_THREADS) {
      int r = idx >> 6, jj = idx & 63;
      float xz = sXpA[r][jj]     + sXpB[r][jj];
      float gz = sGhA[r][jj]     + sGhB[r][jj];
      float xr = sXpA[r][jj+64]  + sXpB[r][jj+64];
      float gr = sGhA[r][jj+64]  + sGhB[r][jj+64];
      float xn = sXpA[r][jj+128] + sXpB[r][jj+128];
      float gn = sGhA[r][jj+128] + sGhB[r][jj+128];
      float z  = sigmoidf_(xz + gz);
      float rg = sigmoidf_(xr + gr);
      float n  = tanhf_(xn + rg * gn);
      sH[r][jj] = (1.f - z)*n + z*sH[r][jj];
    }
    // next iteration's top __syncthreads orders gates before compute
  }
  __syncthreads();
  for (int idx = tid; idx < GRU_ROWS*64; idx += GRU_THREADS) {
    int r = idx >> 6, jj = idx & 63;
    hfin_out[(size_t)(b0 + r)*64 + jj] = sH[r][jj];
  }
}

// ============================================================
// K4: activation unit over the 16 cluster vectors -> ui_l2[b,64]
// ============================================================
__global__ __launch_bounds__(256) void k_act2(
    const int* __restrict__ item_id, const float* __restrict__ emb,
    const float* __restrict__ auW1, const float* __restrict__ auW2,
    const float* __restrict__ aub2,
    const float* __restrict__ qp_in, const float* __restrict__ cluster_in,
    float* __restrict__ ui2_out)
{
  __shared__ float sWk[64*64], sWkq[64*64];
  __shared__ float sQp[64], sItem[64], sW2[64];
  __shared__ float sUi[4][64];
  const int b = blockIdx.x;
  const int tid = threadIdx.x;

  for (int idx = tid; idx < 4096; idx += 256) {
    float a = auW1[idx];
    float c = auW1[2*4096 + idx];
    float d = auW1[3*4096 + idx];
    sWk[idx]  = a + c;
    sWkq[idx] = d;
  }
  if (tid < 64) {
    sW2[tid]   = auW2[tid];
    sQp[tid]   = qp_in[(size_t)b*64 + tid];
    sItem[tid] = emb[(size_t)item_id[b]*64 + tid];
  }
  __syncthreads();

  const int wave = tid >> 6, lane = tid & 63;
  const float q   = sItem[lane];
  const float b2v = aub2[0];
  float accui = 0.f;
  for (int k = wave; k < KA; k += 4) {
    float kv = cluster_in[(size_t)b*(KA*64) + k*64 + lane];
    float kq = kv * q;
    float acc = 0.f;
    #pragma unroll
    for (int i = 0; i < 64; ++i) {
      float ki  = __shfl(kv, i);
      float kqi = __shfl(kq, i);
      acc += ki * sWk[i*64 + lane] + kqi * sWkq[i*64 + lane];
    }
    float hid = fmaxf(acc + sQp[lane], 0.f);
    float w = hid * sW2[lane];
    #pragma unroll
    for (int off = 32; off > 0; off >>= 1) w += __shfl_xor(w, off);
    w += b2v;
    accui += w * kv;
  }
  sUi[wave][lane] = accui;
  __syncthreads();
  if (tid < 64) {
    ui2_out[(size_t)b*64 + tid] =
        sUi[0][tid] + sUi[1][tid] + sUi[2][tid] + sUi[3][tid];
  }
}

// ============================================================
// K5: final MLP: concat -> fc0(relu) -> fc1(relu) -> final -> sigmoid
// ============================================================
#define MLP_ROWS 16
__global__ __launch_bounds__(256) void k_mlp(
    const int* __restrict__ item_id, const float* __restrict__ emb,
    const float* __restrict__ ui1, const float* __restrict__ ui2,
    const float* __restrict__ hfin,
    const float* __restrict__ W0, const float* __restrict__ b0,
    const float* __restrict__ W1, const float* __restrict__ b1,
    const float* __restrict__ fW, const float* __restrict__ fb,
    float* __restrict__ out)
{
  __shared__ float sC[MLP_ROWS][256];
  __shared__ float sX0[MLP_ROWS][256];
  __shared__ float sX1[MLP_ROWS][128];
  const int tid = threadIdx.x;
  const int rb  = blockIdx.x * MLP_ROWS;

  for (int idx = tid; idx < MLP_ROWS*256; idx += 256) {
    int r = idx >> 8, c = idx & 255;
    size_t row = (size_t)(rb + r);
    float v;
    if (c < 64)       v = ui1[row*64 + c];
    else if (c < 128) v = ui2[row*64 + (c-64)];
    else if (c < 192) v = hfin[row*64 + (c-128)];
    else              v = emb[(size_t)item_id[row]*64 + (c-192)];
    sC[r][c] = v;
  }
  __syncthreads();
  {
    float acc[MLP_ROWS];
    #pragma unroll
    for (int r = 0; r < MLP_ROWS; ++r) acc[r] = b0[tid];
    #pragma unroll 4
    for (int i = 0; i < 256; ++i) {
      float w = W0[(size_t)i*256 + tid];
      #pragma unroll
      for (int r = 0; r < MLP_ROWS; ++r) acc[r] += sC[r][i] * w;
    }
    #pragma unroll
    for (int r = 0; r < MLP_ROWS; ++r) sX0[r][tid] = fmaxf(acc[r], 0.f);
  }
  __syncthreads();
  if (tid < 128) {
    float acc[MLP_ROWS];
    #pragma unroll
    for (int r = 0; r < MLP_ROWS; ++r) acc[r] = b1[tid];
    #pragma unroll 4
    for (int i = 0; i < 256; ++i) {
      float w = W1[(size_t)i*128 + tid];
      #pragma unroll
      for (int r = 0; r < MLP_ROWS; ++r) acc[r] += sX0[r][i] * w;
    }
    #pragma unroll
    for (int r = 0; r < MLP_ROWS; ++r) sX1[r][tid] = fmaxf(acc[r], 0.f);
  }
  __syncthreads();
  {
    int r = tid >> 4, l16 = tid & 15;
    float p = 0.f;
    for (int i = l16; i < 128; i += 16) p += sX1[r][i] * fW[i];
    #pragma unroll
    for (int off = 8; off > 0; off >>= 1) p += __shfl_xor(p, off);
    if (l16 == 0) {
      float logit = p + fb[0];
      out[rb + r] = sigmoidf_(logit);
    }
  }
}

// ============================================================
extern "C" void kernel_launch(void* const* d_in, const int* in_sizes, int n_in,
                              void* d_out, int out_size, void* d_ws, size_t ws_size,
                              hipStream_t stream)
{
  const int*   item_id  = (const int*)d_in[0];
  const int*   hist_ids = (const int*)d_in[1];
  const int*   attrs    = (const int*)d_in[2];
  const float* emb      = (const float*)d_in[3];
  const float* auW1     = (const float*)d_in[4];
  const float* aub1     = (const float*)d_in[5];
  const float* auW2     = (const float*)d_in[6];
  const float* aub2     = (const float*)d_in[7];
  const float* gWx      = (const float*)d_in[8];
  const float* gWh      = (const float*)d_in[9];
  const float* gb       = (const float*)d_in[10];
  const float* W0       = (const float*)d_in[11];
  const float* b0       = (const float*)d_in[12];
  const float* W1       = (const float*)d_in[13];
  const float* b1       = (const float*)d_in[14];
  const float* fW       = (const float*)d_in[15];
  const float* fb       = (const float*)d_in[16];

  float* out = (float*)d_out;
  float* ws  = (float*)d_ws;
  float* w1      = ws + OFF_W1;
  float* qp      = ws + OFF_QP;
  float* ui1     = ws + OFF_UI1;
  float* ui2     = ws + OFF_UI2;
  float* hfin    = ws + OFF_HF;
  float* cluster = ws + OFF_CL;

  k_act1<<<B_, 256, 0, stream>>>(item_id, hist_ids, emb, auW1, aub1, auW2,
                                 aub2, w1, qp, ui1);
  k_cluster<<<B_, 256, 0, stream>>>(hist_ids, attrs, emb, w1, cluster);
  k_gru<<<B_/GRU_ROWS, GRU_THREADS, 0, stream>>>(hist_ids, emb, gWx, gWh, gb,
                                                 hfin);
  k_act2<<<B_, 256, 0, stream>>>(item_id, emb, auW1, auW2, aub2, qp, cluster,
                                 ui2);
  k_mlp<<<B_/MLP_ROWS, 256, 0, stream>>>(item_id, emb, ui1, ui2, hfin,
                                         W0, b0, W1, b1, fW, fb, out);
}

// Round 2
// 1278.380 us; speedup vs baseline: 1.8696x; 1.8696x over previous
//
#include <hip/hip_runtime.h>
#include <hip/hip_bf16.h>

#define B_   4096
#define T_   200
#define KA   16

// ---- workspace layout (float offsets) ----
#define OFF_W1  0
#define OFF_QP  (OFF_W1  + B_*T_)
#define OFF_UI1 (OFF_QP  + B_*64)
#define OFF_UI2 (OFF_UI1 + B_*64)
#define OFF_HF  (OFF_UI2 + B_*64)
#define OFF_CL  (OFF_HF  + B_*64)

typedef __attribute__((ext_vector_type(8))) short bf16x8;
typedef __attribute__((ext_vector_type(4))) float f32x4;

__device__ __forceinline__ float sigmoidf_(float x) {
  return 1.f / (1.f + __expf(-x));
}
__device__ __forceinline__ float tanhf_(float x) {
  x = fminf(fmaxf(x, -15.f), 15.f);
  float e = __expf(2.f * x);
  return (e - 1.f) / (e + 1.f);
}
// float -> bf16 (RNE, finite inputs)
__device__ __forceinline__ short f2bf(float x) {
  unsigned u = __float_as_uint(x);
  unsigned r = (u + 0x7fffu + ((u >> 16) & 1u)) >> 16;
  return (short)r;
}

// ============================================================
// K1 (MFMA): activation unit over history.
//   A[t, 0:128] = [K(t) | K(t)*q],  Bw[128,64] = [Wk ; Wkq] (bf16)
//   hid = relu(A@Bw + qp) ; w1 = hid@W2 + b2 ; ui1 = sum_t w1*K
//   Wk = W1[0:64]+W1[128:192], Wkq = W1[192:256]
//   qp = b1 + item@(W1[64:128]-W1[128:192])
// ============================================================
__global__ __launch_bounds__(256) void k_act1(
    const int* __restrict__ item_id, const int* __restrict__ hist_ids,
    const float* __restrict__ emb, const float* __restrict__ auW1,
    const float* __restrict__ aub1, const float* __restrict__ auW2,
    const float* __restrict__ aub2,
    float* __restrict__ w1_out, float* __restrict__ qp_out,
    float* __restrict__ ui1_out)
{
  __shared__ short sB[128*64];   // bf16 [k][j]
  __shared__ float sQp[64];
  __shared__ float sUi[4][64];

  const int b = blockIdx.x;
  const int tid = threadIdx.x;
  const int wave = tid >> 6, lane = tid & 63;
  const int g = lane >> 4;          // k-group 0..3
  const int c15 = lane & 15;

  // stage folded weights as bf16 in LDS (coalesced f32 reads, once/block)
  for (int idx = tid; idx < 64*64; idx += 256) {
    sB[idx]        = f2bf(auW1[idx] + auW1[2*4096 + idx]);  // Wk rows 0..63
    sB[4096 + idx] = f2bf(auW1[3*4096 + idx]);              // Wkq rows 64..127
  }
  const int itrow = item_id[b];
  if (tid < 64) {
    float acc = aub1[tid];
    for (int i = 0; i < 64; ++i) {
      float wq = auW1[(64+i)*64 + tid] - auW1[(128+i)*64 + tid];
      acc += emb[(size_t)itrow*64 + i] * wq;
    }
    sQp[tid] = acc;
    qp_out[(size_t)b*64 + tid] = acc;
  }
  __syncthreads();

  // per-lane q slice: q[g*8 .. g*8+7] and q[32+g*8 .. 32+g*8+7]
  const float4* itemp = (const float4*)(emb + (size_t)itrow*64);
  float4 q0 = itemp[g*2],     q1 = itemp[g*2 + 1];
  float4 q2 = itemp[8 + g*2], q3 = itemp[8 + g*2 + 1];

  // B fragments in registers (reused for all 13 t-tiles)
  bf16x8 bfr[4][4];   // [kk][n]
  #pragma unroll
  for (int kk = 0; kk < 4; ++kk) {
    #pragma unroll
    for (int n = 0; n < 4; ++n) {
      bf16x8 v;
      #pragma unroll
      for (int jj = 0; jj < 8; ++jj)
        v[jj] = sB[(kk*32 + g*8 + jj)*64 + n*16 + c15];
      bfr[kk][n] = v;
    }
  }
  float w2v[4], qpv[4];
  #pragma unroll
  for (int n = 0; n < 4; ++n) {
    w2v[n] = auW2[n*16 + c15];
    qpv[n] = sQp[n*16 + c15];
  }
  const float b2v = aub2[0];

  float ui = 0.f;   // ui1 partial for d = lane
  for (int tt = wave; tt < 13; tt += 4) {
    const int t = tt*16 + c15;
    const bool valid = (t < T_);
    float4 k0{0,0,0,0}, k1{0,0,0,0}, k2{0,0,0,0}, k3{0,0,0,0};
    if (valid) {
      int rid = hist_ids[(size_t)b*T_ + t];
      const float4* kp = (const float4*)(emb + (size_t)rid*64);
      k0 = kp[g*2];     k1 = kp[g*2 + 1];
      k2 = kp[8 + g*2]; k3 = kp[8 + g*2 + 1];
    }
    bf16x8 a0, a1, a2, a3;
    a0[0]=f2bf(k0.x); a0[1]=f2bf(k0.y); a0[2]=f2bf(k0.z); a0[3]=f2bf(k0.w);
    a0[4]=f2bf(k1.x); a0[5]=f2bf(k1.y); a0[6]=f2bf(k1.z); a0[7]=f2bf(k1.w);
    a1[0]=f2bf(k2.x); a1[1]=f2bf(k2.y); a1[2]=f2bf(k2.z); a1[3]=f2bf(k2.w);
    a1[4]=f2bf(k3.x); a1[5]=f2bf(k3.y); a1[6]=f2bf(k3.z); a1[7]=f2bf(k3.w);
    a2[0]=f2bf(k0.x*q0.x); a2[1]=f2bf(k0.y*q0.y); a2[2]=f2bf(k0.z*q0.z); a2[3]=f2bf(k0.w*q0.w);
    a2[4]=f2bf(k1.x*q1.x); a2[5]=f2bf(k1.y*q1.y); a2[6]=f2bf(k1.z*q1.z); a2[7]=f2bf(k1.w*q1.w);
    a3[0]=f2bf(k2.x*q2.x); a3[1]=f2bf(k2.y*q2.y); a3[2]=f2bf(k2.z*q2.z); a3[3]=f2bf(k2.w*q2.w);
    a3[4]=f2bf(k3.x*q3.x); a3[5]=f2bf(k3.y*q3.y); a3[6]=f2bf(k3.z*q3.z); a3[7]=f2bf(k3.w*q3.w);

    f32x4 acc[4];
    #pragma unroll
    for (int n = 0; n < 4; ++n) acc[n] = f32x4{qpv[n], qpv[n], qpv[n], qpv[n]};
    #pragma unroll
    for (int n = 0; n < 4; ++n) {
      acc[n] = __builtin_amdgcn_mfma_f32_16x16x32_bf16(a0, bfr[0][n], acc[n], 0, 0, 0);
      acc[n] = __builtin_amdgcn_mfma_f32_16x16x32_bf16(a1, bfr[1][n], acc[n], 0, 0, 0);
      acc[n] = __builtin_amdgcn_mfma_f32_16x16x32_bf16(a2, bfr[2][n], acc[n], 0, 0, 0);
      acc[n] = __builtin_amdgcn_mfma_f32_16x16x32_bf16(a3, bfr[3][n], acc[n], 0, 0, 0);
    }
    // w-sums per C-row: row = g*4 + r, col = n*16 + c15
    float ws[4] = {0.f, 0.f, 0.f, 0.f};
    #pragma unroll
    for (int n = 0; n < 4; ++n) {
      #pragma unroll
      for (int r = 0; r < 4; ++r)
        ws[r] += fmaxf(acc[n][r], 0.f) * w2v[n];
    }
    #pragma unroll
    for (int r = 0; r < 4; ++r) {
      ws[r] += __shfl_xor(ws[r], 1);
      ws[r] += __shfl_xor(ws[r], 2);
      ws[r] += __shfl_xor(ws[r], 4);
      ws[r] += __shfl_xor(ws[r], 8);
      ws[r] += b2v;
    }
    if (c15 == 0) {
      #pragma unroll
      for (int r = 0; r < 4; ++r) {
        int trow = tt*16 + g*4 + r;
        if (trow < T_) w1_out[(size_t)b*T_ + trow] = ws[r];
      }
    }
    // ui1 partial: redistribute w1 via shfl (compile-time reg index)
    const int nvalid = min(16, T_ - tt*16);
    #pragma unroll
    for (int tp = 0; tp < 16; ++tp) {
      if (tp < nvalid) {
        float w1v = __shfl(ws[tp & 3], (tp >> 2) << 4);
        int id2 = hist_ids[(size_t)b*T_ + tt*16 + tp];
        ui += w1v * emb[(size_t)id2*64 + lane];
      }
    }
  }
  sUi[wave][lane] = ui;
  __syncthreads();
  if (tid < 64) {
    ui1_out[(size_t)b*64 + tid] =
        sUi[0][tid] + sUi[1][tid] + sUi[2][tid] + sUi[3][tid];
  }
}

// ============================================================
// K2: per-attribute masked softmax over t + cluster[b,k,64]
// ============================================================
__global__ __launch_bounds__(256) void k_cluster(
    const int* __restrict__ hist_ids, const int* __restrict__ attrs,
    const float* __restrict__ emb, const float* __restrict__ w1_in,
    float* __restrict__ cluster_out)
{
  __shared__ float sW1[T_];
  __shared__ int sAttr[T_], sIds[T_];
  const int b = blockIdx.x;
  const int tid = threadIdx.x;
  if (tid < T_) {
    sW1[tid]   = w1_in[(size_t)b*T_ + tid];
    sAttr[tid] = attrs[(size_t)b*T_ + tid];
    sIds[tid]  = hist_ids[(size_t)b*T_ + tid];
  }
  __syncthreads();
  const int wave = tid >> 6, lane = tid & 63;
  for (int k = wave; k < KA; k += 4) {
    float m = -1e9f;
    for (int tt = 0; tt < 4; ++tt) {
      int t = tt*64 + lane;
      if (t < T_ && sAttr[t] == k) m = fmaxf(m, sW1[t]);
    }
    #pragma unroll
    for (int off = 32; off > 0; off >>= 1) m = fmaxf(m, __shfl_xor(m, off));
    float e = 0.f;
    for (int tt = 0; tt < 4; ++tt) {
      int t = tt*64 + lane;
      if (t < T_ && sAttr[t] == k) e += expf(sW1[t] - m);
    }
    #pragma unroll
    for (int off = 32; off > 0; off >>= 1) e += __shfl_xor(e, off);
    float cj = 0.f;
    if (e > 0.f) {
      float inv = 1.f / e;
      for (int t = 0; t < T_; ++t) {
        if (sAttr[t] == k) {   // wave-uniform branch
          float p = expf(sW1[t] - m) * inv;
          cj += p * emb[(size_t)sIds[t]*64 + lane];
        }
      }
    }
    cluster_out[(size_t)b*(KA*64) + k*64 + lane] = cj;
  }
}

// ============================================================
// K3: GRU over history, 16 batch rows/block, weights in registers.
// ============================================================
#define GRU_ROWS 16
#define GRU_THREADS 768

__global__ __launch_bounds__(GRU_THREADS) void k_gru(
    const int* __restrict__ hist_ids, const float* __restrict__ emb,
    const float* __restrict__ Wx, const float* __restrict__ Wh,
    const float* __restrict__ gb, float* __restrict__ hfin_out)
{
  __shared__ __align__(16) float sX[GRU_ROWS][64];
  __shared__ __align__(16) float sH[GRU_ROWS][64];
  __shared__ float sXpA[GRU_ROWS][192], sXpB[GRU_ROWS][192];
  __shared__ float sGhA[GRU_ROWS][192], sGhB[GRU_ROWS][192];

  const int tid = threadIdx.x;
  const int b0  = blockIdx.x * GRU_ROWS;
  const int j   = tid % 192;
  const int sg  = tid / 192;
  const int sub = sg & 1;
  const int g   = sg >> 1;

  float rwx[32], rwh[32];
  #pragma unroll
  for (int i = 0; i < 32; ++i) {
    rwx[i] = Wx[(size_t)(sub*32 + i)*192 + j];
    rwh[i] = Wh[(size_t)(sub*32 + i)*192 + j];
  }
  const float bj = gb[j];

  for (int idx = tid; idx < GRU_ROWS*64; idx += GRU_THREADS)
    ((float*)sH)[idx] = 0.f;
  __syncthreads();

  float xa, xb;
  {
    int r1 = hist_ids[(size_t)(b0 + (tid >> 6))*T_ + 0];
    xa = emb[(size_t)r1*64 + (tid & 63)];
    xb = 0.f;
    if (tid < 256) {
      int idx2 = 768 + tid;
      int r2 = hist_ids[(size_t)(b0 + (idx2 >> 6))*T_ + 0];
      xb = emb[(size_t)r2*64 + (idx2 & 63)];
    }
  }

  float (*outXp)[192] = sub ? sXpB : sXpA;
  float (*outGh)[192] = sub ? sGhB : sGhA;

  for (int t = 0; t < T_; ++t) {
    ((float*)sX)[tid] = xa;
    if (tid < 256) ((float*)sX)[768 + tid] = xb;
    __syncthreads();

    if (t + 1 < T_) {
      int r1 = hist_ids[(size_t)(b0 + (tid >> 6))*T_ + (t+1)];
      xa = emb[(size_t)r1*64 + (tid & 63)];
      if (tid < 256) {
        int idx2 = 768 + tid;
        int r2 = hist_ids[(size_t)(b0 + (idx2 >> 6))*T_ + (t+1)];
        xb = emb[(size_t)r2*64 + (idx2 & 63)];
      }
    }

    float ax[8], ah[8];
    #pragma unroll
    for (int rr = 0; rr < 8; ++rr) { ax[rr] = sub ? 0.f : bj; ah[rr] = 0.f; }

    const float4* x4 = (const float4*)sX;
    const float4* h4 = (const float4*)sH;
    #pragma unroll
    for (int i4 = 0; i4 < 8; ++i4) {
      const int f4 = sub*8 + i4;
      #pragma unroll
      for (int rr = 0; rr < 8; ++rr) {
        const int r = g*8 + rr;
        float4 xv = x4[r*16 + f4];
        float4 hv = h4[r*16 + f4];
        ax[rr] += xv.x*rwx[i4*4+0] + xv.y*rwx[i4*4+1]
                + xv.z*rwx[i4*4+2] + xv.w*rwx[i4*4+3];
        ah[rr] += hv.x*rwh[i4*4+0] + hv.y*rwh[i4*4+1]
                + hv.z*rwh[i4*4+2] + hv.w*rwh[i4*4+3];
      }
    }
    #pragma unroll
    for (int rr = 0; rr < 8; ++rr) {
      const int r = g*8 + rr;
      outXp[r][j] = ax[rr];
      outGh[r][j] = ah[rr];
    }
    __syncthreads();

    for (int idx = tid; idx < GRU_ROWS*64; idx += GRU_THREADS) {
      int r = idx >> 6, jj = idx & 63;
      float xz = sXpA[r][jj]     + sXpB[r][jj];
      float gz = sGhA[r][jj]     + sGhB[r][jj];
      float xr = sXpA[r][jj+64]  + sXpB[r][jj+64];
      float gr = sGhA[r][jj+64]  + sGhB[r][jj+64];
      float xn = sXpA[r][jj+128] + sXpB[r][jj+128];
      float gn = sGhA[r][jj+128] + sGhB[r][jj+128];
      float z  = sigmoidf_(xz + gz);
      float rg = sigmoidf_(xr + gr);
      float n  = tanhf_(xn + rg * gn);
      sH[r][jj] = (1.f - z)*n + z*sH[r][jj];
    }
  }
  __syncthreads();
  for (int idx = tid; idx < GRU_ROWS*64; idx += GRU_THREADS) {
    int r = idx >> 6, jj = idx & 63;
    hfin_out[(size_t)(b0 + r)*64 + jj] = sH[r][jj];
  }
}

// ============================================================
// K4: activation unit over the 16 cluster vectors -> ui_l2[b,64]
// ============================================================
__global__ __launch_bounds__(256) void k_act2(
    const int* __restrict__ item_id, const float* __restrict__ emb,
    const float* __restrict__ auW1, const float* __restrict__ auW2,
    const float* __restrict__ aub2,
    const float* __restrict__ qp_in, const float* __restrict__ cluster_in,
    float* __restrict__ ui2_out)
{
  __shared__ float sWk[64*64], sWkq[64*64];
  __shared__ float sQp[64], sItem[64], sW2[64];
  __shared__ float sUi[4][64];
  const int b = blockIdx.x;
  const int tid = threadIdx.x;

  for (int idx = tid; idx < 4096; idx += 256) {
    float a = auW1[idx];
    float c = auW1[2*4096 + idx];
    float d = auW1[3*4096 + idx];
    sWk[idx]  = a + c;
    sWkq[idx] = d;
  }
  if (tid < 64) {
    sW2[tid]   = auW2[tid];
    sQp[tid]   = qp_in[(size_t)b*64 + tid];
    sItem[tid] = emb[(size_t)item_id[b]*64 + tid];
  }
  __syncthreads();

  const int wave = tid >> 6, lane = tid & 63;
  const float q   = sItem[lane];
  const float b2v = aub2[0];
  float accui = 0.f;
  for (int k = wave; k < KA; k += 4) {
    float kv = cluster_in[(size_t)b*(KA*64) + k*64 + lane];
    float kq = kv * q;
    float acc = 0.f;
    #pragma unroll
    for (int i = 0; i < 64; ++i) {
      float ki  = __shfl(kv, i);
      float kqi = __shfl(kq, i);
      acc += ki * sWk[i*64 + lane] + kqi * sWkq[i*64 + lane];
    }
    float hid = fmaxf(acc + sQp[lane], 0.f);
    float w = hid * sW2[lane];
    #pragma unroll
    for (int off = 32; off > 0; off >>= 1) w += __shfl_xor(w, off);
    w += b2v;
    accui += w * kv;
  }
  sUi[wave][lane] = accui;
  __syncthreads();
  if (tid < 64) {
    ui2_out[(size_t)b*64 + tid] =
        sUi[0][tid] + sUi[1][tid] + sUi[2][tid] + sUi[3][tid];
  }
}

// ============================================================
// K5: final MLP
// ============================================================
#define MLP_ROWS 16
__global__ __launch_bounds__(256) void k_mlp(
    const int* __restrict__ item_id, const float* __restrict__ emb,
    const float* __restrict__ ui1, const float* __restrict__ ui2,
    const float* __restrict__ hfin,
    const float* __restrict__ W0, const float* __restrict__ b0,
    const float* __restrict__ W1, const float* __restrict__ b1,
    const float* __restrict__ fW, const float* __restrict__ fb,
    float* __restrict__ out)
{
  __shared__ float sC[MLP_ROWS][256];
  __shared__ float sX0[MLP_ROWS][256];
  __shared__ float sX1[MLP_ROWS][128];
  const int tid = threadIdx.x;
  const int rb  = blockIdx.x * MLP_ROWS;

  for (int idx = tid; idx < MLP_ROWS*256; idx += 256) {
    int r = idx >> 8, c = idx & 255;
    size_t row = (size_t)(rb + r);
    float v;
    if (c < 64)       v = ui1[row*64 + c];
    else if (c < 128) v = ui2[row*64 + (c-64)];
    else if (c < 192) v = hfin[row*64 + (c-128)];
    else              v = emb[(size_t)item_id[row]*64 + (c-192)];
    sC[r][c] = v;
  }
  __syncthreads();
  {
    float acc[MLP_ROWS];
    #pragma unroll
    for (int r = 0; r < MLP_ROWS; ++r) acc[r] = b0[tid];
    #pragma unroll 4
    for (int i = 0; i < 256; ++i) {
      float w = W0[(size_t)i*256 + tid];
      #pragma unroll
      for (int r = 0; r < MLP_ROWS; ++r) acc[r] += sC[r][i] * w;
    }
    #pragma unroll
    for (int r = 0; r < MLP_ROWS; ++r) sX0[r][tid] = fmaxf(acc[r], 0.f);
  }
  __syncthreads();
  if (tid < 128) {
    float acc[MLP_ROWS];
    #pragma unroll
    for (int r = 0; r < MLP_ROWS; ++r) acc[r] = b1[tid];
    #pragma unroll 4
    for (int i = 0; i < 256; ++i) {
      float w = W1[(size_t)i*128 + tid];
      #pragma unroll
      for (int r = 0; r < MLP_ROWS; ++r) acc[r] += sX0[r][i] * w;
    }
    #pragma unroll
    for (int r = 0; r < MLP_ROWS; ++r) sX1[r][tid] = fmaxf(acc[r], 0.f);
  }
  __syncthreads();
  {
    int r = tid >> 4, l16 = tid & 15;
    float p = 0.f;
    for (int i = l16; i < 128; i += 16) p += sX1[r][i] * fW[i];
    #pragma unroll
    for (int off = 8; off > 0; off >>= 1) p += __shfl_xor(p, off);
    if (l16 == 0) {
      float logit = p + fb[0];
      out[rb + r] = sigmoidf_(logit);
    }
  }
}

// ============================================================
extern "C" void kernel_launch(void* const* d_in, const int* in_sizes, int n_in,
                              void* d_out, int out_size, void* d_ws, size_t ws_size,
                              hipStream_t stream)
{
  const int*   item_id  = (const int*)d_in[0];
  const int*   hist_ids = (const int*)d_in[1];
  const int*   attrs    = (const int*)d_in[2];
  const float* emb      = (const float*)d_in[3];
  const float* auW1     = (const float*)d_in[4];
  const float* aub1     = (const float*)d_in[5];
  const float* auW2     = (const float*)d_in[6];
  const float* aub2     = (const float*)d_in[7];
  const float* gWx      = (const float*)d_in[8];
  const float* gWh      = (const float*)d_in[9];
  const float* gb       = (const float*)d_in[10];
  const float* W0       = (const float*)d_in[11];
  const float* b0       = (const float*)d_in[12];
  const float* W1       = (const float*)d_in[13];
  const float* b1       = (const float*)d_in[14];
  const float* fW       = (const float*)d_in[15];
  const float* fb       = (const float*)d_in[16];

  float* out = (float*)d_out;
  float* ws  = (float*)d_ws;
  float* w1      = ws + OFF_W1;
  float* qp      = ws + OFF_QP;
  float* ui1     = ws + OFF_UI1;
  float* ui2     = ws + OFF_UI2;
  float* hfin    = ws + OFF_HF;
  float* cluster = ws + OFF_CL;

  k_act1<<<B_, 256, 0, stream>>>(item_id, hist_ids, emb, auW1, aub1, auW2,
                                 aub2, w1, qp, ui1);
  k_cluster<<<B_, 256, 0, stream>>>(hist_ids, attrs, emb, w1, cluster);
  k_gru<<<B_/GRU_ROWS, GRU_THREADS, 0, stream>>>(hist_ids, emb, gWx, gWh, gb,
                                                 hfin);
  k_act2<<<B_, 256, 0, stream>>>(item_id, emb, auW1, auW2, aub2, qp, cluster,
                                 ui2);
  k_mlp<<<B_/MLP_ROWS, 256, 0, stream>>>(item_id, emb, ui1, ui2, hfin,
                                         W0, b0, W1, b1, fW, fb, out);
}

// Round 5
// 658.921 us; speedup vs baseline: 3.6272x; 1.9401x over previous
//
#include <hip/hip_runtime.h>
#include <hip/hip_bf16.h>

#define B_   4096
#define T_   200
#define KA   16

// ---- workspace layout (float offsets) ----
#define OFF_W1  0
#define OFF_QP  (OFF_W1  + B_*T_)
#define OFF_UI1 (OFF_QP  + B_*64)
#define OFF_UI2 (OFF_UI1 + B_*64)
#define OFF_HF  (OFF_UI2 + B_*64)
#define OFF_CL  (OFF_HF  + B_*64)

typedef __attribute__((ext_vector_type(8))) short bf16x8;
typedef __attribute__((ext_vector_type(4))) float f32x4;

__device__ __forceinline__ float sigmoidf_(float x) {
  return 1.f / (1.f + __expf(-x));
}
__device__ __forceinline__ float tanhf_(float x) {
  x = fminf(fmaxf(x, -15.f), 15.f);
  float e = __expf(2.f * x);
  return (e - 1.f) / (e + 1.f);
}
// fast sigmoid/tanh via v_exp_f32 + v_rcp_f32 (saturation-safe)
__device__ __forceinline__ float sigf(float x) {
  return __builtin_amdgcn_rcpf(1.f + __builtin_amdgcn_exp2f(-1.44269504f * x));
}
__device__ __forceinline__ float tanhfast(float y) {
  return 1.f - 2.f * __builtin_amdgcn_rcpf(1.f + __builtin_amdgcn_exp2f(2.88539008f * y));
}
// float -> bf16 (RNE, finite inputs)
__device__ __forceinline__ short f2bf(float x) {
  unsigned u = __float_as_uint(x);
  unsigned r = (u + 0x7fffu + ((u >> 16) & 1u)) >> 16;
  return (short)r;
}

// ============================================================
// K1 (MFMA): activation unit over history.
// ============================================================
__global__ __launch_bounds__(256) void k_act1(
    const int* __restrict__ item_id, const int* __restrict__ hist_ids,
    const float* __restrict__ emb, const float* __restrict__ auW1,
    const float* __restrict__ aub1, const float* __restrict__ auW2,
    const float* __restrict__ aub2,
    float* __restrict__ w1_out, float* __restrict__ qp_out,
    float* __restrict__ ui1_out)
{
  __shared__ short sB[128*64];   // bf16 [k][j]
  __shared__ float sQp[64];
  __shared__ float sUi[4][64];

  const int b = blockIdx.x;
  const int tid = threadIdx.x;
  const int wave = tid >> 6, lane = tid & 63;
  const int g = lane >> 4;
  const int c15 = lane & 15;

  for (int idx = tid; idx < 64*64; idx += 256) {
    sB[idx]        = f2bf(auW1[idx] + auW1[2*4096 + idx]);
    sB[4096 + idx] = f2bf(auW1[3*4096 + idx]);
  }
  const int itrow = item_id[b];
  if (tid < 64) {
    float acc = aub1[tid];
    for (int i = 0; i < 64; ++i) {
      float wq = auW1[(64+i)*64 + tid] - auW1[(128+i)*64 + tid];
      acc += emb[(size_t)itrow*64 + i] * wq;
    }
    sQp[tid] = acc;
    qp_out[(size_t)b*64 + tid] = acc;
  }
  __syncthreads();

  const float4* itemp = (const float4*)(emb + (size_t)itrow*64);
  float4 q0 = itemp[g*2],     q1 = itemp[g*2 + 1];
  float4 q2 = itemp[8 + g*2], q3 = itemp[8 + g*2 + 1];

  bf16x8 bfr[4][4];
  #pragma unroll
  for (int kk = 0; kk < 4; ++kk) {
    #pragma unroll
    for (int n = 0; n < 4; ++n) {
      bf16x8 v;
      #pragma unroll
      for (int jj = 0; jj < 8; ++jj)
        v[jj] = sB[(kk*32 + g*8 + jj)*64 + n*16 + c15];
      bfr[kk][n] = v;
    }
  }
  float w2v[4], qpv[4];
  #pragma unroll
  for (int n = 0; n < 4; ++n) {
    w2v[n] = auW2[n*16 + c15];
    qpv[n] = sQp[n*16 + c15];
  }
  const float b2v = aub2[0];

  float ui = 0.f;
  for (int tt = wave; tt < 13; tt += 4) {
    const int t = tt*16 + c15;
    const bool valid = (t < T_);
    float4 k0{0,0,0,0}, k1{0,0,0,0}, k2{0,0,0,0}, k3{0,0,0,0};
    if (valid) {
      int rid = hist_ids[(size_t)b*T_ + t];
      const float4* kp = (const float4*)(emb + (size_t)rid*64);
      k0 = kp[g*2];     k1 = kp[g*2 + 1];
      k2 = kp[8 + g*2]; k3 = kp[8 + g*2 + 1];
    }
    bf16x8 a0, a1, a2, a3;
    a0[0]=f2bf(k0.x); a0[1]=f2bf(k0.y); a0[2]=f2bf(k0.z); a0[3]=f2bf(k0.w);
    a0[4]=f2bf(k1.x); a0[5]=f2bf(k1.y); a0[6]=f2bf(k1.z); a0[7]=f2bf(k1.w);
    a1[0]=f2bf(k2.x); a1[1]=f2bf(k2.y); a1[2]=f2bf(k2.z); a1[3]=f2bf(k2.w);
    a1[4]=f2bf(k3.x); a1[5]=f2bf(k3.y); a1[6]=f2bf(k3.z); a1[7]=f2bf(k3.w);
    a2[0]=f2bf(k0.x*q0.x); a2[1]=f2bf(k0.y*q0.y); a2[2]=f2bf(k0.z*q0.z); a2[3]=f2bf(k0.w*q0.w);
    a2[4]=f2bf(k1.x*q1.x); a2[5]=f2bf(k1.y*q1.y); a2[6]=f2bf(k1.z*q1.z); a2[7]=f2bf(k1.w*q1.w);
    a3[0]=f2bf(k2.x*q2.x); a3[1]=f2bf(k2.y*q2.y); a3[2]=f2bf(k2.z*q2.z); a3[3]=f2bf(k2.w*q2.w);
    a3[4]=f2bf(k3.x*q3.x); a3[5]=f2bf(k3.y*q3.y); a3[6]=f2bf(k3.z*q3.z); a3[7]=f2bf(k3.w*q3.w);

    f32x4 acc[4];
    #pragma unroll
    for (int n = 0; n < 4; ++n) acc[n] = f32x4{qpv[n], qpv[n], qpv[n], qpv[n]};
    #pragma unroll
    for (int n = 0; n < 4; ++n) {
      acc[n] = __builtin_amdgcn_mfma_f32_16x16x32_bf16(a0, bfr[0][n], acc[n], 0, 0, 0);
      acc[n] = __builtin_amdgcn_mfma_f32_16x16x32_bf16(a1, bfr[1][n], acc[n], 0, 0, 0);
      acc[n] = __builtin_amdgcn_mfma_f32_16x16x32_bf16(a2, bfr[2][n], acc[n], 0, 0, 0);
      acc[n] = __builtin_amdgcn_mfma_f32_16x16x32_bf16(a3, bfr[3][n], acc[n], 0, 0, 0);
    }
    float ws[4] = {0.f, 0.f, 0.f, 0.f};
    #pragma unroll
    for (int n = 0; n < 4; ++n) {
      #pragma unroll
      for (int r = 0; r < 4; ++r)
        ws[r] += fmaxf(acc[n][r], 0.f) * w2v[n];
    }
    #pragma unroll
    for (int r = 0; r < 4; ++r) {
      ws[r] += __shfl_xor(ws[r], 1);
      ws[r] += __shfl_xor(ws[r], 2);
      ws[r] += __shfl_xor(ws[r], 4);
      ws[r] += __shfl_xor(ws[r], 8);
      ws[r] += b2v;
    }
    if (c15 == 0) {
      #pragma unroll
      for (int r = 0; r < 4; ++r) {
        int trow = tt*16 + g*4 + r;
        if (trow < T_) w1_out[(size_t)b*T_ + trow] = ws[r];
      }
    }
    const int nvalid = min(16, T_ - tt*16);
    #pragma unroll
    for (int tp = 0; tp < 16; ++tp) {
      if (tp < nvalid) {
        float w1v = __shfl(ws[tp & 3], (tp >> 2) << 4);
        int id2 = hist_ids[(size_t)b*T_ + tt*16 + tp];
        ui += w1v * emb[(size_t)id2*64 + lane];
      }
    }
  }
  sUi[wave][lane] = ui;
  __syncthreads();
  if (tid < 64) {
    ui1_out[(size_t)b*64 + tid] =
        sUi[0][tid] + sUi[1][tid] + sUi[2][tid] + sUi[3][tid];
  }
}

// ============================================================
// K2: per-attribute masked softmax over t + cluster[b,k,64]
// ============================================================
__global__ __launch_bounds__(256) void k_cluster(
    const int* __restrict__ hist_ids, const int* __restrict__ attrs,
    const float* __restrict__ emb, const float* __restrict__ w1_in,
    float* __restrict__ cluster_out)
{
  __shared__ float sW1[T_];
  __shared__ int sAttr[T_], sIds[T_];
  const int b = blockIdx.x;
  const int tid = threadIdx.x;
  if (tid < T_) {
    sW1[tid]   = w1_in[(size_t)b*T_ + tid];
    sAttr[tid] = attrs[(size_t)b*T_ + tid];
    sIds[tid]  = hist_ids[(size_t)b*T_ + tid];
  }
  __syncthreads();
  const int wave = tid >> 6, lane = tid & 63;
  for (int k = wave; k < KA; k += 4) {
    float m = -1e9f;
    for (int tt = 0; tt < 4; ++tt) {
      int t = tt*64 + lane;
      if (t < T_ && sAttr[t] == k) m = fmaxf(m, sW1[t]);
    }
    #pragma unroll
    for (int off = 32; off > 0; off >>= 1) m = fmaxf(m, __shfl_xor(m, off));
    float e = 0.f;
    for (int tt = 0; tt < 4; ++tt) {
      int t = tt*64 + lane;
      if (t < T_ && sAttr[t] == k) e += expf(sW1[t] - m);
    }
    #pragma unroll
    for (int off = 32; off > 0; off >>= 1) e += __shfl_xor(e, off);
    float cj = 0.f;
    if (e > 0.f) {
      float inv = 1.f / e;
      for (int t = 0; t < T_; ++t) {
        if (sAttr[t] == k) {
          float p = expf(sW1[t] - m) * inv;
          cj += p * emb[(size_t)sIds[t]*64 + lane];
        }
      }
    }
    cluster_out[(size_t)b*(KA*64) + k*64 + lane] = cj;
  }
}

// ============================================================
// K3 (MFMA): GRU over history. 16 rows/block, 4 waves.
//   Wave w owns gate columns j in [w*16, w*16+16): n-tiles {w, 4+w, 8+w}.
//   h kept in C-layout regs (hold[4]) + bf16 LDS double-buffer for the
//   A-fragment transpose (XOR-swizzled: unit ^= row&7).
// ============================================================
__global__ __launch_bounds__(256) void k_gru(
    const int* __restrict__ hist_ids, const float* __restrict__ emb,
    const float* __restrict__ Wx, const float* __restrict__ Wh,
    const float* __restrict__ gb, float* __restrict__ hfin_out)
{
  __shared__ short sH[2][16*64];   // bf16, swizzled

  const int tid  = threadIdx.x;
  const int w    = tid >> 6;       // wave 0..3
  const int lane = tid & 63;
  const int g    = lane >> 4;      // 0..3
  const int c15  = lane & 15;
  const int b0   = blockIdx.x * 16;

  // --- B fragments (bf16, registers): 3 n-tiles x 2 k-chunks, Wx & Wh ---
  bf16x8 bx[3][2], bh[3][2];
  #pragma unroll
  for (int l = 0; l < 3; ++l) {
    const int jb = (l*4 + w)*16 + c15;
    #pragma unroll
    for (int kk = 0; kk < 2; ++kk) {
      bf16x8 vx, vh;
      #pragma unroll
      for (int e = 0; e < 8; ++e) {
        const int krow = kk*32 + g*8 + e;
        vx[e] = f2bf(Wx[(size_t)krow*192 + jb]);
        vh[e] = f2bf(Wh[(size_t)krow*192 + jb]);
      }
      bx[l][kk] = vx; bh[l][kk] = vh;
    }
  }
  float bias[3];
  #pragma unroll
  for (int l = 0; l < 3; ++l) bias[l] = gb[l*64 + w*16 + c15];

  // LDS element indices (bf16 units), swizzle: unit' = unit ^ (row&7)
  const int rs = c15 & 7;
  const int ridx0 = c15*64 + ((g    ) ^ rs)*8;   // chunk0: k = g*8+e
  const int ridx1 = c15*64 + ((g + 4) ^ rs)*8;   // chunk1: k = 32+g*8+e
  int widx[4];
  {
    const int unit = w*2 + (c15 >> 3);
    #pragma unroll
    for (int r = 0; r < 4; ++r) {
      const int row = g*4 + r;
      widx[r] = row*64 + ((unit ^ (row & 7))*8) + (c15 & 7);
    }
  }

  // zero h(0) buffer
  for (int i = tid; i < 16*64; i += 256) sH[0][i] = 0;

  float hold[4] = {0.f, 0.f, 0.f, 0.f};

  // x(0) gather + id prefetch (2-deep)
  const size_t hb = (size_t)(b0 + c15) * T_;
  int id0 = hist_ids[hb + 0];
  const float4* kp0 = (const float4*)(emb + (size_t)id0*64);
  float4 x0 = kp0[g*2],     x1 = kp0[g*2 + 1];
  float4 x2 = kp0[8 + g*2], x3 = kp0[8 + g*2 + 1];
  int idP1 = hist_ids[hb + 1];
  __syncthreads();

  for (int t = 0; t < T_; ++t) {
    const short* hbuf = sH[t & 1];
    short*       hnxt = sH[(t & 1) ^ 1];

    // 1. prefetch id(t+2)
    const int t2 = (t + 2 < T_) ? (t + 2) : (T_ - 1);
    int idP2 = hist_ids[hb + t2];

    // 2. x(t) A-fragments (cvt from prefetched f32)
    bf16x8 ax0, ax1;
    ax0[0]=f2bf(x0.x); ax0[1]=f2bf(x0.y); ax0[2]=f2bf(x0.z); ax0[3]=f2bf(x0.w);
    ax0[4]=f2bf(x1.x); ax0[5]=f2bf(x1.y); ax0[6]=f2bf(x1.z); ax0[7]=f2bf(x1.w);
    ax1[0]=f2bf(x2.x); ax1[1]=f2bf(x2.y); ax1[2]=f2bf(x2.z); ax1[3]=f2bf(x2.w);
    ax1[4]=f2bf(x3.x); ax1[5]=f2bf(x3.y); ax1[6]=f2bf(x3.z); ax1[7]=f2bf(x3.w);

    // 3. issue x(t+1) gather (latency hidden under MFMA+gates+barrier)
    float4 xn0, xn1, xn2, xn3;
    {
      const float4* kp = (const float4*)(emb + (size_t)idP1*64);
      xn0 = kp[g*2];     xn1 = kp[g*2 + 1];
      xn2 = kp[8 + g*2]; xn3 = kp[8 + g*2 + 1];
    }

    // 4. h(t) A-fragments + MFMA
    bf16x8 ah0 = *(const bf16x8*)&hbuf[ridx0];
    bf16x8 ah1 = *(const bf16x8*)&hbuf[ridx1];
    f32x4 aX[3], aH[3];
    #pragma unroll
    for (int l = 0; l < 3; ++l) {
      aX[l] = f32x4{bias[l], bias[l], bias[l], bias[l]};
      aH[l] = f32x4{0.f, 0.f, 0.f, 0.f};
    }
    #pragma unroll
    for (int l = 0; l < 3; ++l) {
      aX[l] = __builtin_amdgcn_mfma_f32_16x16x32_bf16(ax0, bx[l][0], aX[l], 0, 0, 0);
      aX[l] = __builtin_amdgcn_mfma_f32_16x16x32_bf16(ax1, bx[l][1], aX[l], 0, 0, 0);
      aH[l] = __builtin_amdgcn_mfma_f32_16x16x32_bf16(ah0, bh[l][0], aH[l], 0, 0, 0);
      aH[l] = __builtin_amdgcn_mfma_f32_16x16x32_bf16(ah1, bh[l][1], aH[l], 0, 0, 0);
    }

    // 5. gates (thread-local) + write h(t+1) slice
    #pragma unroll
    for (int r = 0; r < 4; ++r) {
      float z  = sigf(aX[0][r] + aH[0][r]);
      float rr = sigf(aX[1][r] + aH[1][r]);
      float nn = tanhfast(aX[2][r] + rr * aH[2][r]);
      hold[r] = (1.f - z)*nn + z*hold[r];
      hnxt[widx[r]] = f2bf(hold[r]);
    }
    __syncthreads();

    x0 = xn0; x1 = xn1; x2 = xn2; x3 = xn3;
    idP1 = idP2;
  }

  #pragma unroll
  for (int r = 0; r < 4; ++r)
    hfin_out[(size_t)(b0 + g*4 + r)*64 + w*16 + c15] = hold[r];
}

// ============================================================
// K4: activation unit over the 16 cluster vectors -> ui_l2[b,64]
// ============================================================
__global__ __launch_bounds__(256) void k_act2(
    const int* __restrict__ item_id, const float* __restrict__ emb,
    const float* __restrict__ auW1, const float* __restrict__ auW2,
    const float* __restrict__ aub2,
    const float* __restrict__ qp_in, const float* __restrict__ cluster_in,
    float* __restrict__ ui2_out)
{
  __shared__ float sWk[64*64], sWkq[64*64];
  __shared__ float sQp[64], sItem[64], sW2[64];
  __shared__ float sUi[4][64];
  const int b = blockIdx.x;
  const int tid = threadIdx.x;

  for (int idx = tid; idx < 4096; idx += 256) {
    float a = auW1[idx];
    float c = auW1[2*4096 + idx];
    float d = auW1[3*4096 + idx];
    sWk[idx]  = a + c;
    sWkq[idx] = d;
  }
  if (tid < 64) {
    sW2[tid]   = auW2[tid];
    sQp[tid]   = qp_in[(size_t)b*64 + tid];
    sItem[tid] = emb[(size_t)item_id[b]*64 + tid];
  }
  __syncthreads();

  const int wave = tid >> 6, lane = tid & 63;
  const float q   = sItem[lane];
  const float b2v = aub2[0];
  float accui = 0.f;
  for (int k = wave; k < KA; k += 4) {
    float kv = cluster_in[(size_t)b*(KA*64) + k*64 + lane];
    float kq = kv * q;
    float acc = 0.f;
    #pragma unroll
    for (int i = 0; i < 64; ++i) {
      float ki  = __shfl(kv, i);
      float kqi = __shfl(kq, i);
      acc += ki * sWk[i*64 + lane] + kqi * sWkq[i*64 + lane];
    }
    float hid = fmaxf(acc + sQp[lane], 0.f);
    float w = hid * sW2[lane];
    #pragma unroll
    for (int off = 32; off > 0; off >>= 1) w += __shfl_xor(w, off);
    w += b2v;
    accui += w * kv;
  }
  sUi[wave][lane] = accui;
  __syncthreads();
  if (tid < 64) {
    ui2_out[(size_t)b*64 + tid] =
        sUi[0][tid] + sUi[1][tid] + sUi[2][tid] + sUi[3][tid];
  }
}

// ============================================================
// K5: final MLP
// ============================================================
#define MLP_ROWS 16
__global__ __launch_bounds__(256) void k_mlp(
    const int* __restrict__ item_id, const float* __restrict__ emb,
    const float* __restrict__ ui1, const float* __restrict__ ui2,
    const float* __restrict__ hfin,
    const float* __restrict__ W0, const float* __restrict__ b0,
    const float* __restrict__ W1, const float* __restrict__ b1,
    const float* __restrict__ fW, const float* __restrict__ fb,
    float* __restrict__ out)
{
  __shared__ float sC[MLP_ROWS][256];
  __shared__ float sX0[MLP_ROWS][256];
  __shared__ float sX1[MLP_ROWS][128];
  const int tid = threadIdx.x;
  const int rb  = blockIdx.x * MLP_ROWS;

  for (int idx = tid; idx < MLP_ROWS*256; idx += 256) {
    int r = idx >> 8, c = idx & 255;
    size_t row = (size_t)(rb + r);
    float v;
    if (c < 64)       v = ui1[row*64 + c];
    else if (c < 128) v = ui2[row*64 + (c-64)];
    else if (c < 192) v = hfin[row*64 + (c-128)];
    else              v = emb[(size_t)item_id[row]*64 + (c-192)];
    sC[r][c] = v;
  }
  __syncthreads();
  {
    float acc[MLP_ROWS];
    #pragma unroll
    for (int r = 0; r < MLP_ROWS; ++r) acc[r] = b0[tid];
    #pragma unroll 4
    for (int i = 0; i < 256; ++i) {
      float w = W0[(size_t)i*256 + tid];
      #pragma unroll
      for (int r = 0; r < MLP_ROWS; ++r) acc[r] += sC[r][i] * w;
    }
    #pragma unroll
    for (int r = 0; r < MLP_ROWS; ++r) sX0[r][tid] = fmaxf(acc[r], 0.f);
  }
  __syncthreads();
  if (tid < 128) {
    float acc[MLP_ROWS];
    #pragma unroll
    for (int r = 0; r < MLP_ROWS; ++r) acc[r] = b1[tid];
    #pragma unroll 4
    for (int i = 0; i < 256; ++i) {
      float w = W1[(size_t)i*128 + tid];
      #pragma unroll
      for (int r = 0; r < MLP_ROWS; ++r) acc[r] += sX0[r][i] * w;
    }
    #pragma unroll
    for (int r = 0; r < MLP_ROWS; ++r) sX1[r][tid] = fmaxf(acc[r], 0.f);
  }
  __syncthreads();
  {
    int r = tid >> 4, l16 = tid & 15;
    float p = 0.f;
    for (int i = l16; i < 128; i += 16) p += sX1[r][i] * fW[i];
    #pragma unroll
    for (int off = 8; off > 0; off >>= 1) p += __shfl_xor(p, off);
    if (l16 == 0) {
      float logit = p + fb[0];
      out[rb + r] = sigmoidf_(logit);
    }
  }
}

// ============================================================
extern "C" void kernel_launch(void* const* d_in, const int* in_sizes, int n_in,
                              void* d_out, int out_size, void* d_ws, size_t ws_size,
                              hipStream_t stream)
{
  const int*   item_id  = (const int*)d_in[0];
  const int*   hist_ids = (const int*)d_in[1];
  const int*   attrs    = (const int*)d_in[2];
  const float* emb      = (const float*)d_in[3];
  const float* auW1     = (const float*)d_in[4];
  const float* aub1     = (const float*)d_in[5];
  const float* auW2     = (const float*)d_in[6];
  const float* aub2     = (const float*)d_in[7];
  const float* gWx      = (const float*)d_in[8];
  const float* gWh      = (const float*)d_in[9];
  const float* gb       = (const float*)d_in[10];
  const float* W0       = (const float*)d_in[11];
  const float* b0       = (const float*)d_in[12];
  const float* W1       = (const float*)d_in[13];
  const float* b1       = (const float*)d_in[14];
  const float* fW       = (const float*)d_in[15];
  const float* fb       = (const float*)d_in[16];

  float* out = (float*)d_out;
  float* ws  = (float*)d_ws;
  float* w1      = ws + OFF_W1;
  float* qp      = ws + OFF_QP;
  float* ui1     = ws + OFF_UI1;
  float* ui2     = ws + OFF_UI2;
  float* hfin    = ws + OFF_HF;
  float* cluster = ws + OFF_CL;

  k_act1<<<B_, 256, 0, stream>>>(item_id, hist_ids, emb, auW1, aub1, auW2,
                                 aub2, w1, qp, ui1);
  k_cluster<<<B_, 256, 0, stream>>>(hist_ids, attrs, emb, w1, cluster);
  k_gru<<<B_/16, 256, 0, stream>>>(hist_ids, emb, gWx, gWh, gb, hfin);
  k_act2<<<B_, 256, 0, stream>>>(item_id, emb, auW1, auW2, aub2, qp, cluster,
                                 ui2);
  k_mlp<<<B_/MLP_ROWS, 256, 0, stream>>>(item_id, emb, ui1, ui2, hfin,
                                         W0, b0, W1, b1, fW, fb, out);
}

// Round 6
// 482.295 us; speedup vs baseline: 4.9556x; 1.3662x over previous
//
#include <hip/hip_runtime.h>
#include <hip/hip_bf16.h>

#define B_   4096
#define T_   200
#define KA   16

// ---- workspace layout (float offsets) ----
#define OFF_W1  0
#define OFF_QP  (OFF_W1  + B_*T_)
#define OFF_UI1 (OFF_QP  + B_*64)
#define OFF_UI2 (OFF_UI1 + B_*64)
#define OFF_HF  (OFF_UI2 + B_*64)
#define OFF_CL  (OFF_HF  + B_*64)

typedef __attribute__((ext_vector_type(8))) short bf16x8;
typedef __attribute__((ext_vector_type(4))) float f32x4;

__device__ __forceinline__ float sigmoidf_(float x) {
  return 1.f / (1.f + __expf(-x));
}
// fast sigmoid/tanh via v_exp_f32 + v_rcp_f32 (saturation-safe)
__device__ __forceinline__ float sigf(float x) {
  return __builtin_amdgcn_rcpf(1.f + __builtin_amdgcn_exp2f(-1.44269504f * x));
}
__device__ __forceinline__ float tanhfast(float y) {
  return 1.f - 2.f * __builtin_amdgcn_rcpf(1.f + __builtin_amdgcn_exp2f(2.88539008f * y));
}
// float -> bf16 (RNE, finite inputs)
__device__ __forceinline__ short f2bf(float x) {
  unsigned u = __float_as_uint(x);
  unsigned r = (u + 0x7fffu + ((u >> 16) & 1u)) >> 16;
  return (short)r;
}
// packed f32x2 -> bf16x2 in one instruction (low = first operand)
__device__ __forceinline__ unsigned cvtpk(float lo, float hi) {
  unsigned r;
  asm("v_cvt_pk_bf16_f32 %0, %1, %2" : "=v"(r) : "v"(lo), "v"(hi));
  return r;
}
union BF8 { bf16x8 v; unsigned u[4]; };

// build bf16x8 from two float4 (elems f0.xyzw, f1.xyzw)
__device__ __forceinline__ bf16x8 pack8(float4 f0, float4 f1) {
  BF8 a;
  a.u[0] = cvtpk(f0.x, f0.y);
  a.u[1] = cvtpk(f0.z, f0.w);
  a.u[2] = cvtpk(f1.x, f1.y);
  a.u[3] = cvtpk(f1.z, f1.w);
  return a.v;
}
__device__ __forceinline__ bf16x8 pack8m(float4 f0, float4 f1,
                                         float4 q0, float4 q1) {
  BF8 a;
  a.u[0] = cvtpk(f0.x*q0.x, f0.y*q0.y);
  a.u[1] = cvtpk(f0.z*q0.z, f0.w*q0.w);
  a.u[2] = cvtpk(f1.x*q1.x, f1.y*q1.y);
  a.u[3] = cvtpk(f1.z*q1.z, f1.w*q1.w);
  return a.v;
}

// ============================================================
// K1 (MFMA): activation unit over history.
// ============================================================
__global__ __launch_bounds__(256) void k_act1(
    const int* __restrict__ item_id, const int* __restrict__ hist_ids,
    const float* __restrict__ emb, const float* __restrict__ auW1,
    const float* __restrict__ aub1, const float* __restrict__ auW2,
    const float* __restrict__ aub2,
    float* __restrict__ w1_out, float* __restrict__ qp_out,
    float* __restrict__ ui1_out)
{
  __shared__ short sB[128*64];   // bf16 [k][j]
  __shared__ float sQp[64];
  __shared__ float sUi[4][64];

  const int b = blockIdx.x;
  const int tid = threadIdx.x;
  const int wave = tid >> 6, lane = tid & 63;
  const int g = lane >> 4;
  const int c15 = lane & 15;

  for (int idx = tid; idx < 64*64; idx += 256) {
    sB[idx]        = f2bf(auW1[idx] + auW1[2*4096 + idx]);
    sB[4096 + idx] = f2bf(auW1[3*4096 + idx]);
  }
  const int itrow = item_id[b];
  if (tid < 64) {
    float acc = aub1[tid];
    for (int i = 0; i < 64; ++i) {
      float wq = auW1[(64+i)*64 + tid] - auW1[(128+i)*64 + tid];
      acc += emb[(size_t)itrow*64 + i] * wq;
    }
    sQp[tid] = acc;
    qp_out[(size_t)b*64 + tid] = acc;
  }
  __syncthreads();

  const float4* itemp = (const float4*)(emb + (size_t)itrow*64);
  float4 q0 = itemp[g*2],     q1 = itemp[g*2 + 1];
  float4 q2 = itemp[8 + g*2], q3 = itemp[8 + g*2 + 1];

  bf16x8 bfr[4][4];
  #pragma unroll
  for (int kk = 0; kk < 4; ++kk) {
    #pragma unroll
    for (int n = 0; n < 4; ++n) {
      bf16x8 v;
      #pragma unroll
      for (int jj = 0; jj < 8; ++jj)
        v[jj] = sB[(kk*32 + g*8 + jj)*64 + n*16 + c15];
      bfr[kk][n] = v;
    }
  }
  float w2v[4], qpv[4];
  #pragma unroll
  for (int n = 0; n < 4; ++n) {
    w2v[n] = auW2[n*16 + c15];
    qpv[n] = sQp[n*16 + c15];
  }
  const float b2v = aub2[0];

  float ui = 0.f;
  for (int tt = wave; tt < 13; tt += 4) {
    const int t = tt*16 + c15;
    const bool valid = (t < T_);
    float4 k0{0,0,0,0}, k1{0,0,0,0}, k2{0,0,0,0}, k3{0,0,0,0};
    if (valid) {
      int rid = hist_ids[(size_t)b*T_ + t];
      const float4* kp = (const float4*)(emb + (size_t)rid*64);
      k0 = kp[g*2];     k1 = kp[g*2 + 1];
      k2 = kp[8 + g*2]; k3 = kp[8 + g*2 + 1];
    }
    bf16x8 a0 = pack8(k0, k1);
    bf16x8 a1 = pack8(k2, k3);
    bf16x8 a2 = pack8m(k0, k1, q0, q1);
    bf16x8 a3 = pack8m(k2, k3, q2, q3);

    f32x4 acc[4];
    #pragma unroll
    for (int n = 0; n < 4; ++n) acc[n] = f32x4{qpv[n], qpv[n], qpv[n], qpv[n]};
    #pragma unroll
    for (int n = 0; n < 4; ++n) {
      acc[n] = __builtin_amdgcn_mfma_f32_16x16x32_bf16(a0, bfr[0][n], acc[n], 0, 0, 0);
      acc[n] = __builtin_amdgcn_mfma_f32_16x16x32_bf16(a1, bfr[1][n], acc[n], 0, 0, 0);
      acc[n] = __builtin_amdgcn_mfma_f32_16x16x32_bf16(a2, bfr[2][n], acc[n], 0, 0, 0);
      acc[n] = __builtin_amdgcn_mfma_f32_16x16x32_bf16(a3, bfr[3][n], acc[n], 0, 0, 0);
    }
    float ws[4] = {0.f, 0.f, 0.f, 0.f};
    #pragma unroll
    for (int n = 0; n < 4; ++n) {
      #pragma unroll
      for (int r = 0; r < 4; ++r)
        ws[r] += fmaxf(acc[n][r], 0.f) * w2v[n];
    }
    #pragma unroll
    for (int r = 0; r < 4; ++r) {
      ws[r] += __shfl_xor(ws[r], 1);
      ws[r] += __shfl_xor(ws[r], 2);
      ws[r] += __shfl_xor(ws[r], 4);
      ws[r] += __shfl_xor(ws[r], 8);
      ws[r] += b2v;
    }
    if (c15 == 0) {
      #pragma unroll
      for (int r = 0; r < 4; ++r) {
        int trow = tt*16 + g*4 + r;
        if (trow < T_) w1_out[(size_t)b*T_ + trow] = ws[r];
      }
    }
    const int nvalid = min(16, T_ - tt*16);
    #pragma unroll
    for (int tp = 0; tp < 16; ++tp) {
      if (tp < nvalid) {
        float w1v = __shfl(ws[tp & 3], (tp >> 2) << 4);
        int id2 = hist_ids[(size_t)b*T_ + tt*16 + tp];
        ui += w1v * emb[(size_t)id2*64 + lane];
      }
    }
  }
  sUi[wave][lane] = ui;
  __syncthreads();
  if (tid < 64) {
    ui1_out[(size_t)b*64 + tid] =
        sUi[0][tid] + sUi[1][tid] + sUi[2][tid] + sUi[3][tid];
  }
}

// ============================================================
// K2: per-attribute masked softmax + cluster, t-parallel accumulate.
//   Phase A: per-k max/expsum (wave-parallel reduce).
//   Phase B: p[t] in one pass; accumulate into per-wave LDS copies.
// ============================================================
__global__ __launch_bounds__(256) void k_cluster(
    const int* __restrict__ hist_ids, const int* __restrict__ attrs,
    const float* __restrict__ emb, const float* __restrict__ w1_in,
    float* __restrict__ cluster_out)
{
  __shared__ float sW1[T_];
  __shared__ int sAttr[T_], sIds[T_];
  __shared__ float sM[KA], sE[KA];
  __shared__ float sP[T_];
  __shared__ float sAcc[4][KA][64];   // 16 KB, per-wave copies
  const int b = blockIdx.x;
  const int tid = threadIdx.x;
  const int wave = tid >> 6, lane = tid & 63;

  if (tid < T_) {
    sW1[tid]   = w1_in[(size_t)b*T_ + tid];
    sAttr[tid] = attrs[(size_t)b*T_ + tid];
    sIds[tid]  = hist_ids[(size_t)b*T_ + tid];
  }
  for (int i = tid; i < 4*KA*64; i += 256) ((float*)sAcc)[i] = 0.f;
  __syncthreads();

  // Phase A: per-k max and expsum
  for (int k = wave; k < KA; k += 4) {
    float m = -1e9f;
    for (int tt = 0; tt < 4; ++tt) {
      int t = tt*64 + lane;
      if (t < T_ && sAttr[t] == k) m = fmaxf(m, sW1[t]);
    }
    #pragma unroll
    for (int off = 32; off > 0; off >>= 1) m = fmaxf(m, __shfl_xor(m, off));
    float e = 0.f;
    for (int tt = 0; tt < 4; ++tt) {
      int t = tt*64 + lane;
      if (t < T_ && sAttr[t] == k) e += __expf(sW1[t] - m);
    }
    #pragma unroll
    for (int off = 32; off > 0; off >>= 1) e += __shfl_xor(e, off);
    if (lane == 0) { sM[k] = m; sE[k] = e; }
  }
  __syncthreads();

  // p[t] (e >= 1 whenever any t has this attr, so the division is safe)
  if (tid < T_) {
    int k = sAttr[tid];
    float e = sE[k];
    sP[tid] = (e > 0.f) ? __expf(sW1[tid] - sM[k]) * __builtin_amdgcn_rcpf(e) : 0.f;
  }
  __syncthreads();

  // Phase B: t-parallel accumulation, wave-private accumulators
  for (int t = wave; t < T_; t += 4) {
    int k   = sAttr[t];
    float p = sP[t];
    float v = emb[(size_t)sIds[t]*64 + lane];
    sAcc[wave][k][lane] += p * v;
  }
  __syncthreads();

  for (int i = tid; i < KA*64; i += 256) {
    cluster_out[(size_t)b*(KA*64) + i] =
        sAcc[0][0][i] + sAcc[1][0][i] + sAcc[2][0][i] + sAcc[3][0][i];
  }
}

// ============================================================
// K3 (MFMA): GRU. 16 rows/block, 4 waves, 2-deep x prefetch,
//   cvt_pk packing, thread-local gates, swizzled bf16 LDS h-dbuf.
// ============================================================
__global__ __launch_bounds__(256) void k_gru(
    const int* __restrict__ hist_ids, const float* __restrict__ emb,
    const float* __restrict__ Wx, const float* __restrict__ Wh,
    const float* __restrict__ gb, float* __restrict__ hfin_out)
{
  __shared__ short sH[2][16*64];   // bf16, swizzled

  const int tid  = threadIdx.x;
  const int w    = tid >> 6;       // wave 0..3
  const int lane = tid & 63;
  const int g    = lane >> 4;      // 0..3
  const int c15  = lane & 15;
  const int b0   = blockIdx.x * 16;

  // --- B fragments (bf16, registers): 3 n-tiles x 2 k-chunks, Wx & Wh ---
  bf16x8 bx[3][2], bh[3][2];
  #pragma unroll
  for (int l = 0; l < 3; ++l) {
    const int jb = (l*4 + w)*16 + c15;
    #pragma unroll
    for (int kk = 0; kk < 2; ++kk) {
      bf16x8 vx, vh;
      #pragma unroll
      for (int e = 0; e < 8; ++e) {
        const int krow = kk*32 + g*8 + e;
        vx[e] = f2bf(Wx[(size_t)krow*192 + jb]);
        vh[e] = f2bf(Wh[(size_t)krow*192 + jb]);
      }
      bx[l][kk] = vx; bh[l][kk] = vh;
    }
  }
  float bias[3];
  #pragma unroll
  for (int l = 0; l < 3; ++l) bias[l] = gb[l*64 + w*16 + c15];

  // LDS element indices (bf16 units), swizzle: unit' = unit ^ (row&7)
  const int rs = c15 & 7;
  const int ridx0 = c15*64 + ((g    ) ^ rs)*8;
  const int ridx1 = c15*64 + ((g + 4) ^ rs)*8;
  int widx[4];
  {
    const int unit = w*2 + (c15 >> 3);
    #pragma unroll
    for (int r = 0; r < 4; ++r) {
      const int row = g*4 + r;
      widx[r] = row*64 + ((unit ^ (row & 7))*8) + (c15 & 7);
    }
  }

  for (int i = tid; i < 16*64; i += 256) sH[0][i] = 0;

  float hold[4] = {0.f, 0.f, 0.f, 0.f};

  // 2-deep x prefetch: xc = x(t), xn = x(t+1), idN2 = id(t+2)
  const size_t hb = (size_t)(b0 + c15) * T_;
  int ida = hist_ids[hb + 0];
  int idb = hist_ids[hb + 1];
  const float4* kpa = (const float4*)(emb + (size_t)ida*64);
  float4 xc0 = kpa[g*2], xc1 = kpa[g*2+1], xc2 = kpa[8+g*2], xc3 = kpa[8+g*2+1];
  const float4* kpb = (const float4*)(emb + (size_t)idb*64);
  float4 xn0 = kpb[g*2], xn1 = kpb[g*2+1], xn2 = kpb[8+g*2], xn3 = kpb[8+g*2+1];
  int idN2 = hist_ids[hb + 2];
  __syncthreads();

  #pragma unroll 2
  for (int t = 0; t < T_; ++t) {
    const short* hbuf = sH[t & 1];
    short*       hnxt = sH[(t & 1) ^ 1];

    // id(t+3)
    const int t3 = (t + 3 < T_) ? (t + 3) : (T_ - 1);
    int idN3 = hist_ids[hb + t3];

    // x(t) A-fragments (packed cvt)
    bf16x8 ax0 = pack8(xc0, xc1);
    bf16x8 ax1 = pack8(xc2, xc3);

    // issue x(t+2) gather (2 steps of latency cover)
    float4 gx0, gx1, gx2, gx3;
    {
      const float4* kp = (const float4*)(emb + (size_t)idN2*64);
      gx0 = kp[g*2];     gx1 = kp[g*2 + 1];
      gx2 = kp[8 + g*2]; gx3 = kp[8 + g*2 + 1];
    }

    // h(t) A-fragments + MFMA
    bf16x8 ah0 = *(const bf16x8*)&hbuf[ridx0];
    bf16x8 ah1 = *(const bf16x8*)&hbuf[ridx1];
    f32x4 aX[3], aH[3];
    #pragma unroll
    for (int l = 0; l < 3; ++l) {
      aX[l] = f32x4{bias[l], bias[l], bias[l], bias[l]};
      aH[l] = f32x4{0.f, 0.f, 0.f, 0.f};
    }
    #pragma unroll
    for (int l = 0; l < 3; ++l) {
      aH[l] = __builtin_amdgcn_mfma_f32_16x16x32_bf16(ah0, bh[l][0], aH[l], 0, 0, 0);
      aH[l] = __builtin_amdgcn_mfma_f32_16x16x32_bf16(ah1, bh[l][1], aH[l], 0, 0, 0);
      aX[l] = __builtin_amdgcn_mfma_f32_16x16x32_bf16(ax0, bx[l][0], aX[l], 0, 0, 0);
      aX[l] = __builtin_amdgcn_mfma_f32_16x16x32_bf16(ax1, bx[l][1], aX[l], 0, 0, 0);
    }

    // gates (thread-local) + write h(t+1) slice
    #pragma unroll
    for (int r = 0; r < 4; ++r) {
      float z  = sigf(aX[0][r] + aH[0][r]);
      float rr = sigf(aX[1][r] + aH[1][r]);
      float nn = tanhfast(aX[2][r] + rr * aH[2][r]);
      hold[r] = (1.f - z)*nn + z*hold[r];
      hnxt[widx[r]] = f2bf(hold[r]);
    }
    __syncthreads();

    // rotate prefetch pipeline
    xc0 = xn0; xc1 = xn1; xc2 = xn2; xc3 = xn3;
    xn0 = gx0; xn1 = gx1; xn2 = gx2; xn3 = gx3;
    idN2 = idN3;
  }

  #pragma unroll
  for (int r = 0; r < 4; ++r)
    hfin_out[(size_t)(b0 + g*4 + r)*64 + w*16 + c15] = hold[r];
}

// ============================================================
// K4: activation unit over the 16 cluster vectors -> ui_l2[b,64]
// ============================================================
__global__ __launch_bounds__(256) void k_act2(
    const int* __restrict__ item_id, const float* __restrict__ emb,
    const float* __restrict__ auW1, const float* __restrict__ auW2,
    const float* __restrict__ aub2,
    const float* __restrict__ qp_in, const float* __restrict__ cluster_in,
    float* __restrict__ ui2_out)
{
  __shared__ float sWk[64*64], sWkq[64*64];
  __shared__ float sQp[64], sItem[64], sW2[64];
  __shared__ float sUi[4][64];
  const int b = blockIdx.x;
  const int tid = threadIdx.x;

  for (int idx = tid; idx < 4096; idx += 256) {
    float a = auW1[idx];
    float c = auW1[2*4096 + idx];
    float d = auW1[3*4096 + idx];
    sWk[idx]  = a + c;
    sWkq[idx] = d;
  }
  if (tid < 64) {
    sW2[tid]   = auW2[tid];
    sQp[tid]   = qp_in[(size_t)b*64 + tid];
    sItem[tid] = emb[(size_t)item_id[b]*64 + tid];
  }
  __syncthreads();

  const int wave = tid >> 6, lane = tid & 63;
  const float q   = sItem[lane];
  const float b2v = aub2[0];
  float accui = 0.f;
  for (int k = wave; k < KA; k += 4) {
    float kv = cluster_in[(size_t)b*(KA*64) + k*64 + lane];
    float kq = kv * q;
    float acc = 0.f;
    #pragma unroll
    for (int i = 0; i < 64; ++i) {
      float ki  = __shfl(kv, i);
      float kqi = __shfl(kq, i);
      acc += ki * sWk[i*64 + lane] + kqi * sWkq[i*64 + lane];
    }
    float hid = fmaxf(acc + sQp[lane], 0.f);
    float w = hid * sW2[lane];
    #pragma unroll
    for (int off = 32; off > 0; off >>= 1) w += __shfl_xor(w, off);
    w += b2v;
    accui += w * kv;
  }
  sUi[wave][lane] = accui;
  __syncthreads();
  if (tid < 64) {
    ui2_out[(size_t)b*64 + tid] =
        sUi[0][tid] + sUi[1][tid] + sUi[2][tid] + sUi[3][tid];
  }
}

// ============================================================
// K5: final MLP
// ============================================================
#define MLP_ROWS 16
__global__ __launch_bounds__(256) void k_mlp(
    const int* __restrict__ item_id, const float* __restrict__ emb,
    const float* __restrict__ ui1, const float* __restrict__ ui2,
    const float* __restrict__ hfin,
    const float* __restrict__ W0, const float* __restrict__ b0,
    const float* __restrict__ W1, const float* __restrict__ b1,
    const float* __restrict__ fW, const float* __restrict__ fb,
    float* __restrict__ out)
{
  __shared__ float sC[MLP_ROWS][256];
  __shared__ float sX0[MLP_ROWS][256];
  __shared__ float sX1[MLP_ROWS][128];
  const int tid = threadIdx.x;
  const int rb  = blockIdx.x * MLP_ROWS;

  for (int idx = tid; idx < MLP_ROWS*256; idx += 256) {
    int r = idx >> 8, c = idx & 255;
    size_t row = (size_t)(rb + r);
    float v;
    if (c < 64)       v = ui1[row*64 + c];
    else if (c < 128) v = ui2[row*64 + (c-64)];
    else if (c < 192) v = hfin[row*64 + (c-128)];
    else              v = emb[(size_t)item_id[row]*64 + (c-192)];
    sC[r][c] = v;
  }
  __syncthreads();
  {
    float acc[MLP_ROWS];
    #pragma unroll
    for (int r = 0; r < MLP_ROWS; ++r) acc[r] = b0[tid];
    #pragma unroll 4
    for (int i = 0; i < 256; ++i) {
      float w = W0[(size_t)i*256 + tid];
      #pragma unroll
      for (int r = 0; r < MLP_ROWS; ++r) acc[r] += sC[r][i] * w;
    }
    #pragma unroll
    for (int r = 0; r < MLP_ROWS; ++r) sX0[r][tid] = fmaxf(acc[r], 0.f);
  }
  __syncthreads();
  if (tid < 128) {
    float acc[MLP_ROWS];
    #pragma unroll
    for (int r = 0; r < MLP_ROWS; ++r) acc[r] = b1[tid];
    #pragma unroll 4
    for (int i = 0; i < 256; ++i) {
      float w = W1[(size_t)i*128 + tid];
      #pragma unroll
      for (int r = 0; r < MLP_ROWS; ++r) acc[r] += sX0[r][i] * w;
    }
    #pragma unroll
    for (int r = 0; r < MLP_ROWS; ++r) sX1[r][tid] = fmaxf(acc[r], 0.f);
  }
  __syncthreads();
  {
    int r = tid >> 4, l16 = tid & 15;
    float p = 0.f;
    for (int i = l16; i < 128; i += 16) p += sX1[r][i] * fW[i];
    #pragma unroll
    for (int off = 8; off > 0; off >>= 1) p += __shfl_xor(p, off);
    if (l16 == 0) {
      float logit = p + fb[0];
      out[rb + r] = sigmoidf_(logit);
    }
  }
}

// ============================================================
extern "C" void kernel_launch(void* const* d_in, const int* in_sizes, int n_in,
                              void* d_out, int out_size, void* d_ws, size_t ws_size,
                              hipStream_t stream)
{
  const int*   item_id  = (const int*)d_in[0];
  const int*   hist_ids = (const int*)d_in[1];
  const int*   attrs    = (const int*)d_in[2];
  const float* emb      = (const float*)d_in[3];
  const float* auW1     = (const float*)d_in[4];
  const float* aub1     = (const float*)d_in[5];
  const float* auW2     = (const float*)d_in[6];
  const float* aub2     = (const float*)d_in[7];
  const float* gWx      = (const float*)d_in[8];
  const float* gWh      = (const float*)d_in[9];
  const float* gb       = (const float*)d_in[10];
  const float* W0       = (const float*)d_in[11];
  const float* b0       = (const float*)d_in[12];
  const float* W1       = (const float*)d_in[13];
  const float* b1       = (const float*)d_in[14];
  const float* fW       = (const float*)d_in[15];
  const float* fb       = (const float*)d_in[16];

  float* out = (float*)d_out;
  float* ws  = (float*)d_ws;
  float* w1      = ws + OFF_W1;
  float* qp      = ws + OFF_QP;
  float* ui1     = ws + OFF_UI1;
  float* ui2     = ws + OFF_UI2;
  float* hfin    = ws + OFF_HF;
  float* cluster = ws + OFF_CL;

  k_act1<<<B_, 256, 0, stream>>>(item_id, hist_ids, emb, auW1, aub1, auW2,
                                 aub2, w1, qp, ui1);
  k_cluster<<<B_, 256, 0, stream>>>(hist_ids, attrs, emb, w1, cluster);
  k_gru<<<B_/16, 256, 0, stream>>>(hist_ids, emb, gWx, gWh, gb, hfin);
  k_act2<<<B_, 256, 0, stream>>>(item_id, emb, auW1, auW2, aub2, qp, cluster,
                                 ui2);
  k_mlp<<<B_/MLP_ROWS, 256, 0, stream>>>(item_id, emb, ui1, ui2, hfin,
                                         W0, b0, W1, b1, fW, fb, out);
}

// Round 8
// 474.795 us; speedup vs baseline: 5.0338x; 1.0158x over previous
//
#include <hip/hip_runtime.h>
#include <hip/hip_bf16.h>

#define B_   4096
#define T_   200
#define KA   16

// ---- workspace layout (float offsets) ----
#define OFF_BG  0                     // bf16 folded-weight image (8192 shorts)
#define OFF_QP  (OFF_BG  + B_*T_)
#define OFF_UI1 (OFF_QP  + B_*64)
#define OFF_UI2 (OFF_UI1 + B_*64)
#define OFF_HF  (OFF_UI2 + B_*64)
#define OFF_CL  (OFF_HF  + B_*64)

typedef __attribute__((ext_vector_type(8))) short bf16x8;
typedef __attribute__((ext_vector_type(4))) float f32x4;

__device__ __forceinline__ float sigmoidf_(float x) {
  return 1.f / (1.f + __expf(-x));
}
__device__ __forceinline__ float sigf(float x) {
  return __builtin_amdgcn_rcpf(1.f + __builtin_amdgcn_exp2f(-1.44269504f * x));
}
__device__ __forceinline__ float tanhfast(float y) {
  return 1.f - 2.f * __builtin_amdgcn_rcpf(1.f + __builtin_amdgcn_exp2f(2.88539008f * y));
}
__device__ __forceinline__ short f2bf(float x) {
  unsigned u = __float_as_uint(x);
  unsigned r = (u + 0x7fffu + ((u >> 16) & 1u)) >> 16;
  return (short)r;
}
__device__ __forceinline__ unsigned cvtpk(float lo, float hi) {
  unsigned r;
  asm("v_cvt_pk_bf16_f32 %0, %1, %2" : "=v"(r) : "v"(lo), "v"(hi));
  return r;
}
union BF8 { bf16x8 v; unsigned u[4]; };

__device__ __forceinline__ bf16x8 pack8(float4 f0, float4 f1) {
  BF8 a;
  a.u[0] = cvtpk(f0.x, f0.y);
  a.u[1] = cvtpk(f0.z, f0.w);
  a.u[2] = cvtpk(f1.x, f1.y);
  a.u[3] = cvtpk(f1.z, f1.w);
  return a.v;
}
__device__ __forceinline__ bf16x8 pack8m(float4 f0, float4 f1,
                                         float4 q0, float4 q1) {
  BF8 a;
  a.u[0] = cvtpk(f0.x*q0.x, f0.y*q0.y);
  a.u[1] = cvtpk(f0.z*q0.z, f0.w*q0.w);
  a.u[2] = cvtpk(f1.x*q1.x, f1.y*q1.y);
  a.u[3] = cvtpk(f1.z*q1.z, f1.w*q1.w);
  return a.v;
}

// sB2 layout: fragment-contiguous bf16. dst16(k,col) for k=0..127, col=0..63:
//   kk=k>>5, g=(k>>3)&3, jj=k&7  ->  (kk*4+g)*512 + col*8 + jj
// read frag(kk,n,g,c15) = 8 contiguous shorts at (kk*4+g)*512 + (n*16+c15)*8.

// ============================================================
// K1 (MFMA, fused): activation unit over history + attribute-group
// softmax/cluster + ui1.  One block per b.
// ============================================================
__global__ __launch_bounds__(256) void k_act1(
    const int* __restrict__ item_id, const int* __restrict__ hist_ids,
    const int* __restrict__ attrs,
    const float* __restrict__ emb, const float* __restrict__ auW1,
    const float* __restrict__ aub1, const float* __restrict__ auW2,
    const float* __restrict__ aub2,
    float* __restrict__ qp_out, float* __restrict__ ui1_out,
    float* __restrict__ cluster_out, short* __restrict__ bg_out)
{
  __shared__ short sB2[8192];        // 16 KB bf16 folded weights (frag layout)
  __shared__ float sAcc[4][KA][64];  // 16 KB per-wave cluster accum
  __shared__ float sW1[208];
  __shared__ float sP[200];
  __shared__ float sM[KA], sE[KA];
  __shared__ float sItem[64], sQp[64];
  __shared__ float sQpP[4][64];
  __shared__ float sUi[4][64];
  __shared__ int   sIds[200], sAttr[200];

  const int b = blockIdx.x;
  const int tid = threadIdx.x;
  const int wave = tid >> 6, lane = tid & 63;
  const int g = lane >> 4;
  const int c15 = lane & 15;
  const int itrow = item_id[b];

  // --- stage folded weights in frag-contiguous layout ---
  for (int idx = tid; idx < 8192; idx += 256) {
    const int k = idx >> 6, col = idx & 63;
    float v;
    if (k < 64) v = auW1[k*64 + col] + auW1[2*4096 + k*64 + col];
    else        v = auW1[3*4096 + (k-64)*64 + col];
    short bv = f2bf(v);
    int dst = ((k >> 5)*4 + ((k >> 3) & 3))*512 + col*8 + (k & 7);
    sB2[dst] = bv;
    if (b == 0) bg_out[dst] = bv;
  }
  if (tid < 64) sItem[tid] = emb[(size_t)itrow*64 + tid];
  if (tid < T_) {
    sIds[tid]  = hist_ids[(size_t)b*T_ + tid];
    sAttr[tid] = attrs[(size_t)b*T_ + tid];
  }
  for (int i = tid; i < 4*KA*64; i += 256) ((float*)sAcc)[i] = 0.f;
  __syncthreads();

  // --- qp = b1 + item@(W1b - W1c), 256-thread parallel ---
  {
    const int j = tid & 63, iq = tid >> 6;
    float acc = 0.f;
    #pragma unroll
    for (int ii = 0; ii < 16; ++ii) {
      const int i = iq*16 + ii;
      acc += sItem[i] * (auW1[(64+i)*64 + j] - auW1[(128+i)*64 + j]);
    }
    sQpP[iq][j] = acc;
  }
  __syncthreads();
  if (tid < 64) {
    float q = aub1[tid] + sQpP[0][tid] + sQpP[1][tid] + sQpP[2][tid] + sQpP[3][tid];
    sQp[tid] = q;
    qp_out[(size_t)b*64 + tid] = q;
  }
  __syncthreads();

  // --- per-lane fragments ---
  const float4* itemp = (const float4*)(emb + (size_t)itrow*64);
  float4 q0 = itemp[g*2],     q1 = itemp[g*2 + 1];
  float4 q2 = itemp[8 + g*2], q3 = itemp[8 + g*2 + 1];

  bf16x8 bfr[4][4];   // [kk][n]
  #pragma unroll
  for (int kk = 0; kk < 4; ++kk) {
    #pragma unroll
    for (int n = 0; n < 4; ++n)
      bfr[kk][n] = *(const bf16x8*)&sB2[(kk*4 + g)*512 + (n*16 + c15)*8];
  }
  float w2v[4], qpv[4];
  #pragma unroll
  for (int n = 0; n < 4; ++n) {
    w2v[n] = auW2[n*16 + c15];
    qpv[n] = sQp[n*16 + c15];
  }
  const float b2v = aub2[0];

  // --- t-tiles: MFMA act-unit -> w1 scores into LDS ---
  for (int tt = wave; tt < 13; tt += 4) {
    const int t = tt*16 + c15;
    float4 k0{0,0,0,0}, k1{0,0,0,0}, k2{0,0,0,0}, k3{0,0,0,0};
    if (t < T_) {
      const float4* kp = (const float4*)(emb + (size_t)sIds[t]*64);
      k0 = kp[g*2];     k1 = kp[g*2 + 1];
      k2 = kp[8 + g*2]; k3 = kp[8 + g*2 + 1];
    }
    bf16x8 a0 = pack8(k0, k1);
    bf16x8 a1 = pack8(k2, k3);
    bf16x8 a2 = pack8m(k0, k1, q0, q1);
    bf16x8 a3 = pack8m(k2, k3, q2, q3);

    f32x4 acc[4];
    #pragma unroll
    for (int n = 0; n < 4; ++n) acc[n] = f32x4{qpv[n], qpv[n], qpv[n], qpv[n]};
    #pragma unroll
    for (int n = 0; n < 4; ++n) {
      acc[n] = __builtin_amdgcn_mfma_f32_16x16x32_bf16(a0, bfr[0][n], acc[n], 0, 0, 0);
      acc[n] = __builtin_amdgcn_mfma_f32_16x16x32_bf16(a1, bfr[1][n], acc[n], 0, 0, 0);
      acc[n] = __builtin_amdgcn_mfma_f32_16x16x32_bf16(a2, bfr[2][n], acc[n], 0, 0, 0);
      acc[n] = __builtin_amdgcn_mfma_f32_16x16x32_bf16(a3, bfr[3][n], acc[n], 0, 0, 0);
    }
    float ws[4] = {0.f, 0.f, 0.f, 0.f};
    #pragma unroll
    for (int n = 0; n < 4; ++n) {
      #pragma unroll
      for (int r = 0; r < 4; ++r)
        ws[r] += fmaxf(acc[n][r], 0.f) * w2v[n];
    }
    #pragma unroll
    for (int r = 0; r < 4; ++r) {
      ws[r] += __shfl_xor(ws[r], 1);
      ws[r] += __shfl_xor(ws[r], 2);
      ws[r] += __shfl_xor(ws[r], 4);
      ws[r] += __shfl_xor(ws[r], 8);
      ws[r] += b2v;
    }
    if (c15 == 0) {
      #pragma unroll
      for (int r = 0; r < 4; ++r) {
        const int trow = tt*16 + g*4 + r;
        if (trow < T_) sW1[trow] = ws[r];
      }
    }
  }
  __syncthreads();

  // --- softmax phase A: per-k max & expsum ---
  for (int k = wave; k < KA; k += 4) {
    float m = -1e9f;
    for (int tt4 = 0; tt4 < 4; ++tt4) {
      int t = tt4*64 + lane;
      if (t < T_ && sAttr[t] == k) m = fmaxf(m, sW1[t]);
    }
    #pragma unroll
    for (int off = 32; off > 0; off >>= 1) m = fmaxf(m, __shfl_xor(m, off));
    float e = 0.f;
    for (int tt4 = 0; tt4 < 4; ++tt4) {
      int t = tt4*64 + lane;
      if (t < T_ && sAttr[t] == k) e += __expf(sW1[t] - m);
    }
    #pragma unroll
    for (int off = 32; off > 0; off >>= 1) e += __shfl_xor(e, off);
    if (lane == 0) { sM[k] = m; sE[k] = e; }
  }
  __syncthreads();
  if (tid < T_) {
    int k = sAttr[tid];
    float e = sE[k];
    sP[tid] = (e > 0.f) ? __expf(sW1[tid] - sM[k]) * __builtin_amdgcn_rcpf(e) : 0.f;
  }
  __syncthreads();

  // --- phase B: one gather pass -> cluster accum AND ui1 accum ---
  float uiacc = 0.f;
  for (int t = wave; t < T_; t += 4) {
    int k    = sAttr[t];
    float p  = sP[t];
    float wv = sW1[t];
    float v  = emb[(size_t)sIds[t]*64 + lane];
    sAcc[wave][k][lane] += p * v;
    uiacc += wv * v;
  }
  sUi[wave][lane] = uiacc;
  __syncthreads();

  for (int i = tid; i < KA*64; i += 256) {
    cluster_out[(size_t)b*(KA*64) + i] =
        sAcc[0][0][i] + sAcc[1][0][i] + sAcc[2][0][i] + sAcc[3][0][i];
  }
  if (tid < 64) {
    ui1_out[(size_t)b*64 + tid] =
        sUi[0][tid] + sUi[1][tid] + sUi[2][tid] + sUi[3][tid];
  }
}

// ============================================================
// K3 (MFMA): GRU. 8 batch rows/block (2 blocks/CU), 4 waves.
// ============================================================
#define GRU_R 8
__global__ __launch_bounds__(256) void k_gru(
    const int* __restrict__ hist_ids, const float* __restrict__ emb,
    const float* __restrict__ Wx, const float* __restrict__ Wh,
    const float* __restrict__ gb, float* __restrict__ hfin_out)
{
  __shared__ short sH[2][16*64];   // bf16, swizzled; rows 8..15 stay zero

  const int tid  = threadIdx.x;
  const int w    = tid >> 6;
  const int lane = tid & 63;
  const int g    = lane >> 4;
  const int c15  = lane & 15;
  const int b0   = blockIdx.x * GRU_R;

  bf16x8 bx[3][2], bh[3][2];
  #pragma unroll
  for (int l = 0; l < 3; ++l) {
    const int jb = (l*4 + w)*16 + c15;
    #pragma unroll
    for (int kk = 0; kk < 2; ++kk) {
      bf16x8 vx, vh;
      #pragma unroll
      for (int e = 0; e < 8; ++e) {
        const int krow = kk*32 + g*8 + e;
        vx[e] = f2bf(Wx[(size_t)krow*192 + jb]);
        vh[e] = f2bf(Wh[(size_t)krow*192 + jb]);
      }
      bx[l][kk] = vx; bh[l][kk] = vh;
    }
  }
  float bias[3];
  #pragma unroll
  for (int l = 0; l < 3; ++l) bias[l] = gb[l*64 + w*16 + c15];

  const int rs = c15 & 7;
  const int ridx0 = c15*64 + ((g    ) ^ rs)*8;
  const int ridx1 = c15*64 + ((g + 4) ^ rs)*8;
  int widx[4];
  {
    const int unit = w*2 + (c15 >> 3);
    #pragma unroll
    for (int r = 0; r < 4; ++r) {
      const int row = g*4 + r;
      widx[r] = row*64 + ((unit ^ (row & 7))*8) + (c15 & 7);
    }
  }

  // zero BOTH buffers (rows 8..15 never written again)
  for (int i = tid; i < 2*16*64; i += 256) ((short*)sH)[i] = 0;

  float hold[4] = {0.f, 0.f, 0.f, 0.f};

  // 2-deep x prefetch; lanes c15>=8 duplicate rows 0..7 (results discarded)
  const size_t hb = (size_t)(b0 + (c15 & 7)) * T_;
  int ida = hist_ids[hb + 0];
  int idb = hist_ids[hb + 1];
  const float4* kpa = (const float4*)(emb + (size_t)ida*64);
  float4 xc0 = kpa[g*2], xc1 = kpa[g*2+1], xc2 = kpa[8+g*2], xc3 = kpa[8+g*2+1];
  const float4* kpb = (const float4*)(emb + (size_t)idb*64);
  float4 xn0 = kpb[g*2], xn1 = kpb[g*2+1], xn2 = kpb[8+g*2], xn3 = kpb[8+g*2+1];
  int idN2 = hist_ids[hb + 2];
  __syncthreads();

  #pragma unroll 2
  for (int t = 0; t < T_; ++t) {
    const short* hbuf = sH[t & 1];
    short*       hnxt = sH[(t & 1) ^ 1];

    const int t3 = (t + 3 < T_) ? (t + 3) : (T_ - 1);
    int idN3 = hist_ids[hb + t3];

    bf16x8 ax0 = pack8(xc0, xc1);
    bf16x8 ax1 = pack8(xc2, xc3);

    float4 gx0, gx1, gx2, gx3;
    {
      const float4* kp = (const float4*)(emb + (size_t)idN2*64);
      gx0 = kp[g*2];     gx1 = kp[g*2 + 1];
      gx2 = kp[8 + g*2]; gx3 = kp[8 + g*2 + 1];
    }

    bf16x8 ah0 = *(const bf16x8*)&hbuf[ridx0];
    bf16x8 ah1 = *(const bf16x8*)&hbuf[ridx1];
    f32x4 aX[3], aH[3];
    #pragma unroll
    for (int l = 0; l < 3; ++l) {
      aX[l] = f32x4{bias[l], bias[l], bias[l], bias[l]};
      aH[l] = f32x4{0.f, 0.f, 0.f, 0.f};
    }
    #pragma unroll
    for (int l = 0; l < 3; ++l) {
      aH[l] = __builtin_amdgcn_mfma_f32_16x16x32_bf16(ah0, bh[l][0], aH[l], 0, 0, 0);
      aH[l] = __builtin_amdgcn_mfma_f32_16x16x32_bf16(ah1, bh[l][1], aH[l], 0, 0, 0);
      aX[l] = __builtin_amdgcn_mfma_f32_16x16x32_bf16(ax0, bx[l][0], aX[l], 0, 0, 0);
      aX[l] = __builtin_amdgcn_mfma_f32_16x16x32_bf16(ax1, bx[l][1], aX[l], 0, 0, 0);
    }

    #pragma unroll
    for (int r = 0; r < 4; ++r) {
      float z  = sigf(aX[0][r] + aH[0][r]);
      float rr = sigf(aX[1][r] + aH[1][r]);
      float nn = tanhfast(aX[2][r] + rr * aH[2][r]);
      hold[r] = nn + z * (hold[r] - nn);
      if (g < 2) hnxt[widx[r]] = f2bf(hold[r]);
    }
    __syncthreads();

    xc0 = xn0; xc1 = xn1; xc2 = xn2; xc3 = xn3;
    xn0 = gx0; xn1 = gx1; xn2 = gx2; xn3 = gx3;
    idN2 = idN3;
  }

  if (g < 2) {
    #pragma unroll
    for (int r = 0; r < 4; ++r)
      hfin_out[(size_t)(b0 + g*4 + r)*64 + w*16 + c15] = hold[r];
  }
}

// ============================================================
// K4 (MFMA): activation unit over 16 clusters -> ui_l2[b,64]
// ============================================================
__global__ __launch_bounds__(256) void k_act2(
    const int* __restrict__ item_id, const float* __restrict__ emb,
    const float* __restrict__ auW2, const float* __restrict__ aub2,
    const float* __restrict__ qp_in, const float* __restrict__ cluster_in,
    const short* __restrict__ bg_in, float* __restrict__ ui2_out)
{
  __shared__ short sB2[8192];
  __shared__ float sWs[4][16];
  __shared__ float sWf[16];
  __shared__ float sUi[4][64];

  const int b = blockIdx.x;
  const int tid = threadIdx.x;
  const int wave = tid >> 6, lane = tid & 63;
  const int g = lane >> 4;
  const int c15 = lane & 15;
  const int itrow = item_id[b];

  // FIX (R7 bug): sB2 is 8192 shorts = 4096 dwords; was copying only 2048.
  for (int i = tid; i < 4096; i += 256)
    ((unsigned*)sB2)[i] = ((const unsigned*)bg_in)[i];
  __syncthreads();

  // A fragments: rows = 16 clusters (k=c15), feature dim 128 = [C | C*q]
  const float4* itemp = (const float4*)(emb + (size_t)itrow*64);
  float4 q0 = itemp[g*2],     q1 = itemp[g*2 + 1];
  float4 q2 = itemp[8 + g*2], q3 = itemp[8 + g*2 + 1];
  const float4* kp = (const float4*)(cluster_in + (size_t)b*(KA*64) + c15*64);
  float4 k0 = kp[g*2],     k1 = kp[g*2 + 1];
  float4 k2 = kp[8 + g*2], k3 = kp[8 + g*2 + 1];
  bf16x8 a0 = pack8(k0, k1);
  bf16x8 a1 = pack8(k2, k3);
  bf16x8 a2 = pack8m(k0, k1, q0, q1);
  bf16x8 a3 = pack8m(k2, k3, q2, q3);

  // wave w owns n-tile w
  const float qpv = qp_in[(size_t)b*64 + wave*16 + c15];
  const float w2v = auW2[wave*16 + c15];
  f32x4 acc = f32x4{qpv, qpv, qpv, qpv};
  acc = __builtin_amdgcn_mfma_f32_16x16x32_bf16(a0, *(const bf16x8*)&sB2[(0*4+g)*512 + (wave*16+c15)*8], acc, 0, 0, 0);
  acc = __builtin_amdgcn_mfma_f32_16x16x32_bf16(a1, *(const bf16x8*)&sB2[(1*4+g)*512 + (wave*16+c15)*8], acc, 0, 0, 0);
  acc = __builtin_amdgcn_mfma_f32_16x16x32_bf16(a2, *(const bf16x8*)&sB2[(2*4+g)*512 + (wave*16+c15)*8], acc, 0, 0, 0);
  acc = __builtin_amdgcn_mfma_f32_16x16x32_bf16(a3, *(const bf16x8*)&sB2[(3*4+g)*512 + (wave*16+c15)*8], acc, 0, 0, 0);

  float ws[4];
  #pragma unroll
  for (int r = 0; r < 4; ++r) {
    float v = fmaxf(acc[r], 0.f) * w2v;
    v += __shfl_xor(v, 1);
    v += __shfl_xor(v, 2);
    v += __shfl_xor(v, 4);
    v += __shfl_xor(v, 8);
    ws[r] = v;
  }
  if (c15 == 0) {
    #pragma unroll
    for (int r = 0; r < 4; ++r) sWs[wave][g*4 + r] = ws[r];
  }
  __syncthreads();
  if (tid < KA)
    sWf[tid] = sWs[0][tid] + sWs[1][tid] + sWs[2][tid] + sWs[3][tid] + aub2[0];
  __syncthreads();

  float uiacc = 0.f;
  #pragma unroll
  for (int kk = 0; kk < 4; ++kk) {
    const int k = wave*4 + kk;
    uiacc += sWf[k] * cluster_in[(size_t)b*(KA*64) + k*64 + lane];
  }
  sUi[wave][lane] = uiacc;
  __syncthreads();
  if (tid < 64) {
    ui2_out[(size_t)b*64 + tid] =
        sUi[0][tid] + sUi[1][tid] + sUi[2][tid] + sUi[3][tid];
  }
}

// ============================================================
// K5: final MLP
// ============================================================
#define MLP_ROWS 16
__global__ __launch_bounds__(256) void k_mlp(
    const int* __restrict__ item_id, const float* __restrict__ emb,
    const float* __restrict__ ui1, const float* __restrict__ ui2,
    const float* __restrict__ hfin,
    const float* __restrict__ W0, const float* __restrict__ b0,
    const float* __restrict__ W1, const float* __restrict__ b1,
    const float* __restrict__ fW, const float* __restrict__ fb,
    float* __restrict__ out)
{
  __shared__ float sC[MLP_ROWS][256];
  __shared__ float sX0[MLP_ROWS][256];
  __shared__ float sX1[MLP_ROWS][128];
  const int tid = threadIdx.x;
  const int rb  = blockIdx.x * MLP_ROWS;

  for (int idx = tid; idx < MLP_ROWS*256; idx += 256) {
    int r = idx >> 8, c = idx & 255;
    size_t row = (size_t)(rb + r);
    float v;
    if (c < 64)       v = ui1[row*64 + c];
    else if (c < 128) v = ui2[row*64 + (c-64)];
    else if (c < 192) v = hfin[row*64 + (c-128)];
    else              v = emb[(size_t)item_id[row]*64 + (c-192)];
    sC[r][c] = v;
  }
  __syncthreads();
  {
    float acc[MLP_ROWS];
    #pragma unroll
    for (int r = 0; r < MLP_ROWS; ++r) acc[r] = b0[tid];
    #pragma unroll 4
    for (int i = 0; i < 256; ++i) {
      float w = W0[(size_t)i*256 + tid];
      #pragma unroll
      for (int r = 0; r < MLP_ROWS; ++r) acc[r] += sC[r][i] * w;
    }
    #pragma unroll
    for (int r = 0; r < MLP_ROWS; ++r) sX0[r][tid] = fmaxf(acc[r], 0.f);
  }
  __syncthreads();
  if (tid < 128) {
    float acc[MLP_ROWS];
    #pragma unroll
    for (int r = 0; r < MLP_ROWS; ++r) acc[r] = b1[tid];
    #pragma unroll 4
    for (int i = 0; i < 256; ++i) {
      float w = W1[(size_t)i*128 + tid];
      #pragma unroll
      for (int r = 0; r < MLP_ROWS; ++r) acc[r] += sX0[r][i] * w;
    }
    #pragma unroll
    for (int r = 0; r < MLP_ROWS; ++r) sX1[r][tid] = fmaxf(acc[r], 0.f);
  }
  __syncthreads();
  {
    int r = tid >> 4, l16 = tid & 15;
    float p = 0.f;
    for (int i = l16; i < 128; i += 16) p += sX1[r][i] * fW[i];
    #pragma unroll
    for (int off = 8; off > 0; off >>= 1) p += __shfl_xor(p, off);
    if (l16 == 0) {
      float logit = p + fb[0];
      out[rb + r] = sigmoidf_(logit);
    }
  }
}

// ============================================================
extern "C" void kernel_launch(void* const* d_in, const int* in_sizes, int n_in,
                              void* d_out, int out_size, void* d_ws, size_t ws_size,
                              hipStream_t stream)
{
  const int*   item_id  = (const int*)d_in[0];
  const int*   hist_ids = (const int*)d_in[1];
  const int*   attrs    = (const int*)d_in[2];
  const float* emb      = (const float*)d_in[3];
  const float* auW1     = (const float*)d_in[4];
  const float* aub1     = (const float*)d_in[5];
  const float* auW2     = (const float*)d_in[6];
  const float* aub2     = (const float*)d_in[7];
  const float* gWx      = (const float*)d_in[8];
  const float* gWh      = (const float*)d_in[9];
  const float* gb       = (const float*)d_in[10];
  const float* W0       = (const float*)d_in[11];
  const float* b0       = (const float*)d_in[12];
  const float* W1       = (const float*)d_in[13];
  const float* b1       = (const float*)d_in[14];
  const float* fW       = (const float*)d_in[15];
  const float* fb       = (const float*)d_in[16];

  float* out = (float*)d_out;
  float* ws  = (float*)d_ws;
  short* bg      = (short*)(ws + OFF_BG);
  float* qp      = ws + OFF_QP;
  float* ui1     = ws + OFF_UI1;
  float* ui2     = ws + OFF_UI2;
  float* hfin    = ws + OFF_HF;
  float* cluster = ws + OFF_CL;

  k_act1<<<B_, 256, 0, stream>>>(item_id, hist_ids, attrs, emb, auW1, aub1,
                                 auW2, aub2, qp, ui1, cluster, bg);
  k_gru<<<B_/GRU_R, 256, 0, stream>>>(hist_ids, emb, gWx, gWh, gb, hfin);
  k_act2<<<B_, 256, 0, stream>>>(item_id, emb, auW2, aub2, qp, cluster, bg,
                                 ui2);
  k_mlp<<<B_/MLP_ROWS, 256, 0, stream>>>(item_id, emb, ui1, ui2, hfin,
                                         W0, b0, W1, b1, fW, fb, out);
}

// Round 9
// 361.646 us; speedup vs baseline: 6.6088x; 1.3129x over previous
//
#include <hip/hip_runtime.h>
#include <hip/hip_bf16.h>

#define B_   4096
#define T_   200
#define KA   16

// ---- workspace layout (float offsets) ----
#define OFF_BG  0                     // bf16 folded-weight image (8192 shorts)
#define OFF_QP  (OFF_BG  + B_*T_)
#define OFF_UI1 (OFF_QP  + B_*64)
#define OFF_UI2 (OFF_UI1 + B_*64)
#define OFF_HF  (OFF_UI2 + B_*64)
#define OFF_CL  (OFF_HF  + B_*64)

typedef __attribute__((ext_vector_type(8))) short bf16x8;
typedef __attribute__((ext_vector_type(4))) float f32x4;

__device__ __forceinline__ float sigmoidf_(float x) {
  return 1.f / (1.f + __expf(-x));
}
__device__ __forceinline__ float sigf(float x) {
  return __builtin_amdgcn_rcpf(1.f + __builtin_amdgcn_exp2f(-1.44269504f * x));
}
__device__ __forceinline__ float tanhfast(float y) {
  return 1.f - 2.f * __builtin_amdgcn_rcpf(1.f + __builtin_amdgcn_exp2f(2.88539008f * y));
}
__device__ __forceinline__ short f2bf(float x) {
  unsigned u = __float_as_uint(x);
  unsigned r = (u + 0x7fffu + ((u >> 16) & 1u)) >> 16;
  return (short)r;
}
__device__ __forceinline__ unsigned cvtpk(float lo, float hi) {
  unsigned r;
  asm("v_cvt_pk_bf16_f32 %0, %1, %2" : "=v"(r) : "v"(lo), "v"(hi));
  return r;
}
union BF8 { bf16x8 v; unsigned u[4]; };

__device__ __forceinline__ bf16x8 pack8(float4 f0, float4 f1) {
  BF8 a;
  a.u[0] = cvtpk(f0.x, f0.y);
  a.u[1] = cvtpk(f0.z, f0.w);
  a.u[2] = cvtpk(f1.x, f1.y);
  a.u[3] = cvtpk(f1.z, f1.w);
  return a.v;
}
__device__ __forceinline__ bf16x8 pack8m(float4 f0, float4 f1,
                                         float4 q0, float4 q1) {
  BF8 a;
  a.u[0] = cvtpk(f0.x*q0.x, f0.y*q0.y);
  a.u[1] = cvtpk(f0.z*q0.z, f0.w*q0.w);
  a.u[2] = cvtpk(f1.x*q1.x, f1.y*q1.y);
  a.u[3] = cvtpk(f1.z*q1.z, f1.w*q1.w);
  return a.v;
}

// sB2 layout: fragment-contiguous bf16. dst16(k,col) for k=0..127, col=0..63:
//   kk=k>>5, g=(k>>3)&3, jj=k&7  ->  (kk*4+g)*512 + col*8 + jj

// ============================================================
// K1 (MFMA, fused): activation unit over history + attribute-group
// softmax/cluster + ui1.  One block per b.  (unchanged from R8, passing)
// ============================================================
__global__ __launch_bounds__(256) void k_act1(
    const int* __restrict__ item_id, const int* __restrict__ hist_ids,
    const int* __restrict__ attrs,
    const float* __restrict__ emb, const float* __restrict__ auW1,
    const float* __restrict__ aub1, const float* __restrict__ auW2,
    const float* __restrict__ aub2,
    float* __restrict__ qp_out, float* __restrict__ ui1_out,
    float* __restrict__ cluster_out, short* __restrict__ bg_out)
{
  __shared__ short sB2[8192];
  __shared__ float sAcc[4][KA][64];
  __shared__ float sW1[208];
  __shared__ float sP[200];
  __shared__ float sM[KA], sE[KA];
  __shared__ float sItem[64], sQp[64];
  __shared__ float sQpP[4][64];
  __shared__ float sUi[4][64];
  __shared__ int   sIds[200], sAttr[200];

  const int b = blockIdx.x;
  const int tid = threadIdx.x;
  const int wave = tid >> 6, lane = tid & 63;
  const int g = lane >> 4;
  const int c15 = lane & 15;
  const int itrow = item_id[b];

  for (int idx = tid; idx < 8192; idx += 256) {
    const int k = idx >> 6, col = idx & 63;
    float v;
    if (k < 64) v = auW1[k*64 + col] + auW1[2*4096 + k*64 + col];
    else        v = auW1[3*4096 + (k-64)*64 + col];
    short bv = f2bf(v);
    int dst = ((k >> 5)*4 + ((k >> 3) & 3))*512 + col*8 + (k & 7);
    sB2[dst] = bv;
    if (b == 0) bg_out[dst] = bv;
  }
  if (tid < 64) sItem[tid] = emb[(size_t)itrow*64 + tid];
  if (tid < T_) {
    sIds[tid]  = hist_ids[(size_t)b*T_ + tid];
    sAttr[tid] = attrs[(size_t)b*T_ + tid];
  }
  for (int i = tid; i < 4*KA*64; i += 256) ((float*)sAcc)[i] = 0.f;
  __syncthreads();

  {
    const int j = tid & 63, iq = tid >> 6;
    float acc = 0.f;
    #pragma unroll
    for (int ii = 0; ii < 16; ++ii) {
      const int i = iq*16 + ii;
      acc += sItem[i] * (auW1[(64+i)*64 + j] - auW1[(128+i)*64 + j]);
    }
    sQpP[iq][j] = acc;
  }
  __syncthreads();
  if (tid < 64) {
    float q = aub1[tid] + sQpP[0][tid] + sQpP[1][tid] + sQpP[2][tid] + sQpP[3][tid];
    sQp[tid] = q;
    qp_out[(size_t)b*64 + tid] = q;
  }
  __syncthreads();

  const float4* itemp = (const float4*)(emb + (size_t)itrow*64);
  float4 q0 = itemp[g*2],     q1 = itemp[g*2 + 1];
  float4 q2 = itemp[8 + g*2], q3 = itemp[8 + g*2 + 1];

  bf16x8 bfr[4][4];
  #pragma unroll
  for (int kk = 0; kk < 4; ++kk) {
    #pragma unroll
    for (int n = 0; n < 4; ++n)
      bfr[kk][n] = *(const bf16x8*)&sB2[(kk*4 + g)*512 + (n*16 + c15)*8];
  }
  float w2v[4], qpv[4];
  #pragma unroll
  for (int n = 0; n < 4; ++n) {
    w2v[n] = auW2[n*16 + c15];
    qpv[n] = sQp[n*16 + c15];
  }
  const float b2v = aub2[0];

  for (int tt = wave; tt < 13; tt += 4) {
    const int t = tt*16 + c15;
    float4 k0{0,0,0,0}, k1{0,0,0,0}, k2{0,0,0,0}, k3{0,0,0,0};
    if (t < T_) {
      const float4* kp = (const float4*)(emb + (size_t)sIds[t]*64);
      k0 = kp[g*2];     k1 = kp[g*2 + 1];
      k2 = kp[8 + g*2]; k3 = kp[8 + g*2 + 1];
    }
    bf16x8 a0 = pack8(k0, k1);
    bf16x8 a1 = pack8(k2, k3);
    bf16x8 a2 = pack8m(k0, k1, q0, q1);
    bf16x8 a3 = pack8m(k2, k3, q2, q3);

    f32x4 acc[4];
    #pragma unroll
    for (int n = 0; n < 4; ++n) acc[n] = f32x4{qpv[n], qpv[n], qpv[n], qpv[n]};
    #pragma unroll
    for (int n = 0; n < 4; ++n) {
      acc[n] = __builtin_amdgcn_mfma_f32_16x16x32_bf16(a0, bfr[0][n], acc[n], 0, 0, 0);
      acc[n] = __builtin_amdgcn_mfma_f32_16x16x32_bf16(a1, bfr[1][n], acc[n], 0, 0, 0);
      acc[n] = __builtin_amdgcn_mfma_f32_16x16x32_bf16(a2, bfr[2][n], acc[n], 0, 0, 0);
      acc[n] = __builtin_amdgcn_mfma_f32_16x16x32_bf16(a3, bfr[3][n], acc[n], 0, 0, 0);
    }
    float ws[4] = {0.f, 0.f, 0.f, 0.f};
    #pragma unroll
    for (int n = 0; n < 4; ++n) {
      #pragma unroll
      for (int r = 0; r < 4; ++r)
        ws[r] += fmaxf(acc[n][r], 0.f) * w2v[n];
    }
    #pragma unroll
    for (int r = 0; r < 4; ++r) {
      ws[r] += __shfl_xor(ws[r], 1);
      ws[r] += __shfl_xor(ws[r], 2);
      ws[r] += __shfl_xor(ws[r], 4);
      ws[r] += __shfl_xor(ws[r], 8);
      ws[r] += b2v;
    }
    if (c15 == 0) {
      #pragma unroll
      for (int r = 0; r < 4; ++r) {
        const int trow = tt*16 + g*4 + r;
        if (trow < T_) sW1[trow] = ws[r];
      }
    }
  }
  __syncthreads();

  for (int k = wave; k < KA; k += 4) {
    float m = -1e9f;
    for (int tt4 = 0; tt4 < 4; ++tt4) {
      int t = tt4*64 + lane;
      if (t < T_ && sAttr[t] == k) m = fmaxf(m, sW1[t]);
    }
    #pragma unroll
    for (int off = 32; off > 0; off >>= 1) m = fmaxf(m, __shfl_xor(m, off));
    float e = 0.f;
    for (int tt4 = 0; tt4 < 4; ++tt4) {
      int t = tt4*64 + lane;
      if (t < T_ && sAttr[t] == k) e += __expf(sW1[t] - m);
    }
    #pragma unroll
    for (int off = 32; off > 0; off >>= 1) e += __shfl_xor(e, off);
    if (lane == 0) { sM[k] = m; sE[k] = e; }
  }
  __syncthreads();
  if (tid < T_) {
    int k = sAttr[tid];
    float e = sE[k];
    sP[tid] = (e > 0.f) ? __expf(sW1[tid] - sM[k]) * __builtin_amdgcn_rcpf(e) : 0.f;
  }
  __syncthreads();

  float uiacc = 0.f;
  for (int t = wave; t < T_; t += 4) {
    int k    = sAttr[t];
    float p  = sP[t];
    float wv = sW1[t];
    float v  = emb[(size_t)sIds[t]*64 + lane];
    sAcc[wave][k][lane] += p * v;
    uiacc += wv * v;
  }
  sUi[wave][lane] = uiacc;
  __syncthreads();

  for (int i = tid; i < KA*64; i += 256) {
    cluster_out[(size_t)b*(KA*64) + i] =
        sAcc[0][0][i] + sAcc[1][0][i] + sAcc[2][0][i] + sAcc[3][0][i];
  }
  if (tid < 64) {
    ui1_out[(size_t)b*64 + tid] =
        sUi[0][tid] + sUi[1][tid] + sUi[2][tid] + sUi[3][tid];
  }
}

// ============================================================
// K3 (MFMA): GRU, 16 rows/block, producer-consumer.
//   512 threads: waves 0..3 compute (R6 structure), waves 4..7 stage
//   x(t+2) -> 4-deep swizzled bf16 LDS ring.  1 barrier/step.
// ============================================================
#define GRU_ROWS 16
__global__ __launch_bounds__(512) void k_gru(
    const int* __restrict__ hist_ids, const float* __restrict__ emb,
    const float* __restrict__ Wx, const float* __restrict__ Wh,
    const float* __restrict__ gb, float* __restrict__ hfin_out)
{
  __shared__ short sH[2][16*64];    // h double-buffer (swizzled)
  __shared__ short sX[4][16*64];    // x ring (same swizzle)
  __shared__ int   sIds[16*200];

  const int tid  = threadIdx.x;
  const int w    = tid >> 6;        // 0..7
  const int lane = tid & 63;
  const int g    = lane >> 4;
  const int c15  = lane & 15;
  const int b0   = blockIdx.x * GRU_ROWS;

  // all: stage ids + zero h(0)
  for (int i = tid; i < 16*200; i += 512) {
    const int r = i / 200, t = i - r*200;
    sIds[i] = hist_ids[(size_t)(b0 + r)*T_ + t];
  }
  for (int i = tid; i < 16*64; i += 512) sH[0][i] = 0;
  __syncthreads();

  if (w >= 4) {
    // ---------- staging waves ----------
    const int stane = (w - 4)*64 + lane;       // 0..255
    const int srow  = stane >> 4;              // 0..15
    const int scol  = (stane & 15) * 4;        // 0,4,...,60
    const int sidx  = srow*64 + (((scol >> 3) ^ (srow & 7))*8) + (scol & 7);
    const int* idrow = &sIds[srow*200];
    #pragma unroll
    for (int p = 0; p < 2; ++p) {              // prologue x(0), x(1)
      const float4 f = *(const float4*)(emb + (size_t)idrow[p]*64 + scol);
      uint2 u; u.x = cvtpk(f.x, f.y); u.y = cvtpk(f.z, f.w);
      *(uint2*)&sX[p][sidx] = u;
    }
    __syncthreads();                           // matches compute's pre-loop barrier
    for (int t = 0; t < T_; ++t) {
      const int t2 = (t + 2 < T_) ? (t + 2) : (T_ - 1);
      const float4 f = *(const float4*)(emb + (size_t)idrow[t2]*64 + scol);
      uint2 u; u.x = cvtpk(f.x, f.y); u.y = cvtpk(f.z, f.w);
      *(uint2*)&sX[(t + 2) & 3][sidx] = u;
      __syncthreads();
    }
  } else {
    // ---------- compute waves (R6 structure, x from LDS ring) ----------
    bf16x8 bx[3][2], bh[3][2];
    #pragma unroll
    for (int l = 0; l < 3; ++l) {
      const int jb = (l*4 + w)*16 + c15;
      #pragma unroll
      for (int kk = 0; kk < 2; ++kk) {
        bf16x8 vx, vh;
        #pragma unroll
        for (int e = 0; e < 8; ++e) {
          const int krow = kk*32 + g*8 + e;
          vx[e] = f2bf(Wx[(size_t)krow*192 + jb]);
          vh[e] = f2bf(Wh[(size_t)krow*192 + jb]);
        }
        bx[l][kk] = vx; bh[l][kk] = vh;
      }
    }
    float bias[3];
    #pragma unroll
    for (int l = 0; l < 3; ++l) bias[l] = gb[l*64 + w*16 + c15];

    const int rs = c15 & 7;
    const int ridx0 = c15*64 + ((g    ) ^ rs)*8;
    const int ridx1 = c15*64 + ((g + 4) ^ rs)*8;
    int widx[4];
    {
      const int unit = w*2 + (c15 >> 3);
      #pragma unroll
      for (int r = 0; r < 4; ++r) {
        const int row = g*4 + r;
        widx[r] = row*64 + ((unit ^ (row & 7))*8) + (c15 & 7);
      }
    }
    float hold[4] = {0.f, 0.f, 0.f, 0.f};
    __syncthreads();                           // matches staging prologue barrier

    #pragma unroll 2
    for (int t = 0; t < T_; ++t) {
      const short* hbuf = sH[t & 1];
      short*       hnxt = sH[(t & 1) ^ 1];
      const short* xbuf = sX[t & 3];

      bf16x8 ax0 = *(const bf16x8*)&xbuf[ridx0];
      bf16x8 ax1 = *(const bf16x8*)&xbuf[ridx1];
      bf16x8 ah0 = *(const bf16x8*)&hbuf[ridx0];
      bf16x8 ah1 = *(const bf16x8*)&hbuf[ridx1];

      f32x4 aX[3], aH[3];
      #pragma unroll
      for (int l = 0; l < 3; ++l) {
        aX[l] = f32x4{bias[l], bias[l], bias[l], bias[l]};
        aH[l] = f32x4{0.f, 0.f, 0.f, 0.f};
      }
      #pragma unroll
      for (int l = 0; l < 3; ++l) {
        aH[l] = __builtin_amdgcn_mfma_f32_16x16x32_bf16(ah0, bh[l][0], aH[l], 0, 0, 0);
        aH[l] = __builtin_amdgcn_mfma_f32_16x16x32_bf16(ah1, bh[l][1], aH[l], 0, 0, 0);
        aX[l] = __builtin_amdgcn_mfma_f32_16x16x32_bf16(ax0, bx[l][0], aX[l], 0, 0, 0);
        aX[l] = __builtin_amdgcn_mfma_f32_16x16x32_bf16(ax1, bx[l][1], aX[l], 0, 0, 0);
      }

      #pragma unroll
      for (int r = 0; r < 4; ++r) {
        float z  = sigf(aX[0][r] + aH[0][r]);
        float rr = sigf(aX[1][r] + aH[1][r]);
        float nn = tanhfast(aX[2][r] + rr * aH[2][r]);
        hold[r] = nn + z * (hold[r] - nn);
        hnxt[widx[r]] = f2bf(hold[r]);
      }
      __syncthreads();
    }

    #pragma unroll
    for (int r = 0; r < 4; ++r)
      hfin_out[(size_t)(b0 + g*4 + r)*64 + w*16 + c15] = hold[r];
  }
}

// ============================================================
// K4 (MFMA): activation unit over 16 clusters -> ui_l2[b,64]
// (unchanged from R8, passing)
// ============================================================
__global__ __launch_bounds__(256) void k_act2(
    const int* __restrict__ item_id, const float* __restrict__ emb,
    const float* __restrict__ auW2, const float* __restrict__ aub2,
    const float* __restrict__ qp_in, const float* __restrict__ cluster_in,
    const short* __restrict__ bg_in, float* __restrict__ ui2_out)
{
  __shared__ short sB2[8192];
  __shared__ float sWs[4][16];
  __shared__ float sWf[16];
  __shared__ float sUi[4][64];

  const int b = blockIdx.x;
  const int tid = threadIdx.x;
  const int wave = tid >> 6, lane = tid & 63;
  const int g = lane >> 4;
  const int c15 = lane & 15;
  const int itrow = item_id[b];

  for (int i = tid; i < 4096; i += 256)
    ((unsigned*)sB2)[i] = ((const unsigned*)bg_in)[i];
  __syncthreads();

  const float4* itemp = (const float4*)(emb + (size_t)itrow*64);
  float4 q0 = itemp[g*2],     q1 = itemp[g*2 + 1];
  float4 q2 = itemp[8 + g*2], q3 = itemp[8 + g*2 + 1];
  const float4* kp = (const float4*)(cluster_in + (size_t)b*(KA*64) + c15*64);
  float4 k0 = kp[g*2],     k1 = kp[g*2 + 1];
  float4 k2 = kp[8 + g*2], k3 = kp[8 + g*2 + 1];
  bf16x8 a0 = pack8(k0, k1);
  bf16x8 a1 = pack8(k2, k3);
  bf16x8 a2 = pack8m(k0, k1, q0, q1);
  bf16x8 a3 = pack8m(k2, k3, q2, q3);

  const float qpv = qp_in[(size_t)b*64 + wave*16 + c15];
  const float w2v = auW2[wave*16 + c15];
  f32x4 acc = f32x4{qpv, qpv, qpv, qpv};
  acc = __builtin_amdgcn_mfma_f32_16x16x32_bf16(a0, *(const bf16x8*)&sB2[(0*4+g)*512 + (wave*16+c15)*8], acc, 0, 0, 0);
  acc = __builtin_amdgcn_mfma_f32_16x16x32_bf16(a1, *(const bf16x8*)&sB2[(1*4+g)*512 + (wave*16+c15)*8], acc, 0, 0, 0);
  acc = __builtin_amdgcn_mfma_f32_16x16x32_bf16(a2, *(const bf16x8*)&sB2[(2*4+g)*512 + (wave*16+c15)*8], acc, 0, 0, 0);
  acc = __builtin_amdgcn_mfma_f32_16x16x32_bf16(a3, *(const bf16x8*)&sB2[(3*4+g)*512 + (wave*16+c15)*8], acc, 0, 0, 0);

  float ws[4];
  #pragma unroll
  for (int r = 0; r < 4; ++r) {
    float v = fmaxf(acc[r], 0.f) * w2v;
    v += __shfl_xor(v, 1);
    v += __shfl_xor(v, 2);
    v += __shfl_xor(v, 4);
    v += __shfl_xor(v, 8);
    ws[r] = v;
  }
  if (c15 == 0) {
    #pragma unroll
    for (int r = 0; r < 4; ++r) sWs[wave][g*4 + r] = ws[r];
  }
  __syncthreads();
  if (tid < KA)
    sWf[tid] = sWs[0][tid] + sWs[1][tid] + sWs[2][tid] + sWs[3][tid] + aub2[0];
  __syncthreads();

  float uiacc = 0.f;
  #pragma unroll
  for (int kk = 0; kk < 4; ++kk) {
    const int k = wave*4 + kk;
    uiacc += sWf[k] * cluster_in[(size_t)b*(KA*64) + k*64 + lane];
  }
  sUi[wave][lane] = uiacc;
  __syncthreads();
  if (tid < 64) {
    ui2_out[(size_t)b*64 + tid] =
        sUi[0][tid] + sUi[1][tid] + sUi[2][tid] + sUi[3][tid];
  }
}

// ============================================================
// K5: final MLP (unchanged)
// ============================================================
#define MLP_ROWS 16
__global__ __launch_bounds__(256) void k_mlp(
    const int* __restrict__ item_id, const float* __restrict__ emb,
    const float* __restrict__ ui1, const float* __restrict__ ui2,
    const float* __restrict__ hfin,
    const float* __restrict__ W0, const float* __restrict__ b0,
    const float* __restrict__ W1, const float* __restrict__ b1,
    const float* __restrict__ fW, const float* __restrict__ fb,
    float* __restrict__ out)
{
  __shared__ float sC[MLP_ROWS][256];
  __shared__ float sX0[MLP_ROWS][256];
  __shared__ float sX1[MLP_ROWS][128];
  const int tid = threadIdx.x;
  const int rb  = blockIdx.x * MLP_ROWS;

  for (int idx = tid; idx < MLP_ROWS*256; idx += 256) {
    int r = idx >> 8, c = idx & 255;
    size_t row = (size_t)(rb + r);
    float v;
    if (c < 64)       v = ui1[row*64 + c];
    else if (c < 128) v = ui2[row*64 + (c-64)];
    else if (c < 192) v = hfin[row*64 + (c-128)];
    else              v = emb[(size_t)item_id[row]*64 + (c-192)];
    sC[r][c] = v;
  }
  __syncthreads();
  {
    float acc[MLP_ROWS];
    #pragma unroll
    for (int r = 0; r < MLP_ROWS; ++r) acc[r] = b0[tid];
    #pragma unroll 4
    for (int i = 0; i < 256; ++i) {
      float w = W0[(size_t)i*256 + tid];
      #pragma unroll
      for (int r = 0; r < MLP_ROWS; ++r) acc[r] += sC[r][i] * w;
    }
    #pragma unroll
    for (int r = 0; r < MLP_ROWS; ++r) sX0[r][tid] = fmaxf(acc[r], 0.f);
  }
  __syncthreads();
  if (tid < 128) {
    float acc[MLP_ROWS];
    #pragma unroll
    for (int r = 0; r < MLP_ROWS; ++r) acc[r] = b1[tid];
    #pragma unroll 4
    for (int i = 0; i < 256; ++i) {
      float w = W1[(size_t)i*128 + tid];
      #pragma unroll
      for (int r = 0; r < MLP_ROWS; ++r) acc[r] += sX0[r][i] * w;
    }
    #pragma unroll
    for (int r = 0; r < MLP_ROWS; ++r) sX1[r][tid] = fmaxf(acc[r], 0.f);
  }
  __syncthreads();
  {
    int r = tid >> 4, l16 = tid & 15;
    float p = 0.f;
    for (int i = l16; i < 128; i += 16) p += sX1[r][i] * fW[i];
    #pragma unroll
    for (int off = 8; off > 0; off >>= 1) p += __shfl_xor(p, off);
    if (l16 == 0) {
      float logit = p + fb[0];
      out[rb + r] = sigmoidf_(logit);
    }
  }
}

// ============================================================
extern "C" void kernel_launch(void* const* d_in, const int* in_sizes, int n_in,
                              void* d_out, int out_size, void* d_ws, size_t ws_size,
                              hipStream_t stream)
{
  const int*   item_id  = (const int*)d_in[0];
  const int*   hist_ids = (const int*)d_in[1];
  const int*   attrs    = (const int*)d_in[2];
  const float* emb      = (const float*)d_in[3];
  const float* auW1     = (const float*)d_in[4];
  const float* aub1     = (const float*)d_in[5];
  const float* auW2     = (const float*)d_in[6];
  const float* aub2     = (const float*)d_in[7];
  const float* gWx      = (const float*)d_in[8];
  const float* gWh      = (const float*)d_in[9];
  const float* gb       = (const float*)d_in[10];
  const float* W0       = (const float*)d_in[11];
  const float* b0       = (const float*)d_in[12];
  const float* W1       = (const float*)d_in[13];
  const float* b1       = (const float*)d_in[14];
  const float* fW       = (const float*)d_in[15];
  const float* fb       = (const float*)d_in[16];

  float* out = (float*)d_out;
  float* ws  = (float*)d_ws;
  short* bg      = (short*)(ws + OFF_BG);
  float* qp      = ws + OFF_QP;
  float* ui1     = ws + OFF_UI1;
  float* ui2     = ws + OFF_UI2;
  float* hfin    = ws + OFF_HF;
  float* cluster = ws + OFF_CL;

  k_act1<<<B_, 256, 0, stream>>>(item_id, hist_ids, attrs, emb, auW1, aub1,
                                 auW2, aub2, qp, ui1, cluster, bg);
  k_gru<<<B_/GRU_ROWS, 512, 0, stream>>>(hist_ids, emb, gWx, gWh, gb, hfin);
  k_act2<<<B_, 256, 0, stream>>>(item_id, emb, auW2, aub2, qp, cluster, bg,
                                 ui2);
  k_mlp<<<B_/MLP_ROWS, 256, 0, stream>>>(item_id, emb, ui1, ui2, hfin,
                                         W0, b0, W1, b1, fW, fb, out);
}

// Round 10
// 324.576 us; speedup vs baseline: 7.3636x; 1.1142x over previous
//
#include <hip/hip_runtime.h>
#include <hip/hip_bf16.h>

#define B_   4096
#define T_   200
#define KA   16

// ---- workspace layout (float offsets) ----
#define OFF_BG  0                     // bf16 weight image: 8192 shorts = 4096 f32 slots
#define OFF_WQ  4096                  // prefolded qp weight, f32 [64][64]
#define OFF_QP  (OFF_BG  + B_*T_)
#define OFF_UI1 (OFF_QP  + B_*64)
#define OFF_UI2 (OFF_UI1 + B_*64)
#define OFF_HF  (OFF_UI2 + B_*64)
#define OFF_CL  (OFF_HF  + B_*64)

typedef __attribute__((ext_vector_type(8))) short bf16x8;
typedef __attribute__((ext_vector_type(4))) float f32x4;

__device__ __forceinline__ float sigmoidf_(float x) {
  return 1.f / (1.f + __expf(-x));
}
__device__ __forceinline__ float sigf(float x) {
  return __builtin_amdgcn_rcpf(1.f + __builtin_amdgcn_exp2f(-1.44269504f * x));
}
__device__ __forceinline__ float tanhfast(float y) {
  return 1.f - 2.f * __builtin_amdgcn_rcpf(1.f + __builtin_amdgcn_exp2f(2.88539008f * y));
}
__device__ __forceinline__ short f2bf(float x) {
  unsigned u = __float_as_uint(x);
  unsigned r = (u + 0x7fffu + ((u >> 16) & 1u)) >> 16;
  return (short)r;
}
__device__ __forceinline__ unsigned cvtpk(float lo, float hi) {
  unsigned r;
  asm("v_cvt_pk_bf16_f32 %0, %1, %2" : "=v"(r) : "v"(lo), "v"(hi));
  return r;
}
union BF8 { bf16x8 v; unsigned u[4]; };

__device__ __forceinline__ bf16x8 pack8(float4 f0, float4 f1) {
  BF8 a;
  a.u[0] = cvtpk(f0.x, f0.y);
  a.u[1] = cvtpk(f0.z, f0.w);
  a.u[2] = cvtpk(f1.x, f1.y);
  a.u[3] = cvtpk(f1.z, f1.w);
  return a.v;
}
__device__ __forceinline__ bf16x8 pack8m(float4 f0, float4 f1,
                                         float4 q0, float4 q1) {
  BF8 a;
  a.u[0] = cvtpk(f0.x*q0.x, f0.y*q0.y);
  a.u[1] = cvtpk(f0.z*q0.z, f0.w*q0.w);
  a.u[2] = cvtpk(f1.x*q1.x, f1.y*q1.y);
  a.u[3] = cvtpk(f1.z*q1.z, f1.w*q1.w);
  return a.v;
}

// bg layout: fragment-contiguous bf16. For k=0..127, col=0..63:
//   dst = ((k>>5)*4 + ((k>>3)&3))*512 + col*8 + (k&7)
// frag(kk,n,g,c15) = 8 contiguous shorts at (kk*4+g)*512 + (n*16+c15)*8.

// ============================================================
// K0: one-shot weight prep: bg (bf16 frag image) + Wq (f32 qp weight)
// ============================================================
__global__ __launch_bounds__(256) void k_prep(
    const float* __restrict__ auW1, short* __restrict__ bg,
    float* __restrict__ wq)
{
  const int i = blockIdx.x*256 + threadIdx.x;   // 48*256 = 12288
  if (i < 8192) {
    const int k = i >> 6, col = i & 63;
    float v;
    if (k < 64) v = auW1[k*64 + col] + auW1[2*4096 + k*64 + col];
    else        v = auW1[3*4096 + (k-64)*64 + col];
    bg[((k >> 5)*4 + ((k >> 3) & 3))*512 + col*8 + (k & 7)] = f2bf(v);
  } else if (i < 12288) {
    const int j = i - 8192;                     // j = i*64+col index
    wq[j] = auW1[(64 + (j >> 6))*64 + (j & 63)]
          - auW1[(128 + (j >> 6))*64 + (j & 63)];
  }
}

// ============================================================
// K1 (MFMA, fused): activation unit over history + attribute-group
// softmax/cluster + ui1.  sAcc overlays sB2 (temporally disjoint).
// ============================================================
__global__ __launch_bounds__(256) void k_act1(
    const int* __restrict__ item_id, const int* __restrict__ hist_ids,
    const int* __restrict__ attrs,
    const float* __restrict__ emb, const float* __restrict__ aub1,
    const float* __restrict__ auW2, const float* __restrict__ aub2,
    const short* __restrict__ bg_in, const float* __restrict__ wq_in,
    float* __restrict__ qp_out, float* __restrict__ ui1_out,
    float* __restrict__ cluster_out)
{
  __shared__ __align__(16) char sPool[16384];   // sB2 (16KB) then sAcc (16KB)
  __shared__ float sW1[208];
  __shared__ float sP[200];
  __shared__ float sM[KA], sE[KA];
  __shared__ float sItem[64], sQp[64];
  __shared__ float sQpP[4][64];
  __shared__ float sUi[4][64];
  __shared__ int   sIds[200], sAttr[200];

  short* sB2 = (short*)sPool;
  float (*sAcc)[KA][64] = (float (*)[KA][64])sPool;

  const int b = blockIdx.x;
  const int tid = threadIdx.x;
  const int wave = tid >> 6, lane = tid & 63;
  const int g = lane >> 4;
  const int c15 = lane & 15;
  const int itrow = item_id[b];

  // --- linear copy of prebuilt weight image (conflict-free, L2-hot) ---
  for (int i = tid; i < 4096; i += 256)
    ((unsigned*)sB2)[i] = ((const unsigned*)bg_in)[i];
  if (tid < 64) sItem[tid] = emb[(size_t)itrow*64 + tid];
  if (tid < T_) {
    sIds[tid]  = hist_ids[(size_t)b*T_ + tid];
    sAttr[tid] = attrs[(size_t)b*T_ + tid];
  }
  __syncthreads();

  // --- qp = b1 + item@Wq (prefolded), 256-thread parallel ---
  {
    const int j = tid & 63, iq = tid >> 6;
    float acc = 0.f;
    #pragma unroll
    for (int ii = 0; ii < 16; ++ii) {
      const int i = iq*16 + ii;
      acc += sItem[i] * wq_in[i*64 + j];
    }
    sQpP[iq][j] = acc;
  }
  __syncthreads();
  if (tid < 64) {
    float q = aub1[tid] + sQpP[0][tid] + sQpP[1][tid] + sQpP[2][tid] + sQpP[3][tid];
    sQp[tid] = q;
    qp_out[(size_t)b*64 + tid] = q;
  }
  __syncthreads();

  // --- per-lane fragments (after this, sB2 is dead) ---
  const float4* itemp = (const float4*)(emb + (size_t)itrow*64);
  float4 q0 = itemp[g*2],     q1 = itemp[g*2 + 1];
  float4 q2 = itemp[8 + g*2], q3 = itemp[8 + g*2 + 1];

  bf16x8 bfr[4][4];
  #pragma unroll
  for (int kk = 0; kk < 4; ++kk) {
    #pragma unroll
    for (int n = 0; n < 4; ++n)
      bfr[kk][n] = *(const bf16x8*)&sB2[(kk*4 + g)*512 + (n*16 + c15)*8];
  }
  float w2v[4], qpv[4];
  #pragma unroll
  for (int n = 0; n < 4; ++n) {
    w2v[n] = auW2[n*16 + c15];
    qpv[n] = sQp[n*16 + c15];
  }
  const float b2v = aub2[0];
  __syncthreads();                 // all waves done reading sB2

  // overlay: zero sAcc (the same 16KB)
  for (int i = tid; i < 4*KA*64; i += 256) ((float*)sAcc)[i] = 0.f;

  // --- t-tiles: MFMA act-unit -> w1 scores into LDS ---
  for (int tt = wave; tt < 13; tt += 4) {
    const int t = tt*16 + c15;
    float4 k0{0,0,0,0}, k1{0,0,0,0}, k2{0,0,0,0}, k3{0,0,0,0};
    if (t < T_) {
      const float4* kp = (const float4*)(emb + (size_t)sIds[t]*64);
      k0 = kp[g*2];     k1 = kp[g*2 + 1];
      k2 = kp[8 + g*2]; k3 = kp[8 + g*2 + 1];
    }
    bf16x8 a0 = pack8(k0, k1);
    bf16x8 a1 = pack8(k2, k3);
    bf16x8 a2 = pack8m(k0, k1, q0, q1);
    bf16x8 a3 = pack8m(k2, k3, q2, q3);

    f32x4 acc[4];
    #pragma unroll
    for (int n = 0; n < 4; ++n) acc[n] = f32x4{qpv[n], qpv[n], qpv[n], qpv[n]};
    #pragma unroll
    for (int n = 0; n < 4; ++n) {
      acc[n] = __builtin_amdgcn_mfma_f32_16x16x32_bf16(a0, bfr[0][n], acc[n], 0, 0, 0);
      acc[n] = __builtin_amdgcn_mfma_f32_16x16x32_bf16(a1, bfr[1][n], acc[n], 0, 0, 0);
      acc[n] = __builtin_amdgcn_mfma_f32_16x16x32_bf16(a2, bfr[2][n], acc[n], 0, 0, 0);
      acc[n] = __builtin_amdgcn_mfma_f32_16x16x32_bf16(a3, bfr[3][n], acc[n], 0, 0, 0);
    }
    float ws[4] = {0.f, 0.f, 0.f, 0.f};
    #pragma unroll
    for (int n = 0; n < 4; ++n) {
      #pragma unroll
      for (int r = 0; r < 4; ++r)
        ws[r] += fmaxf(acc[n][r], 0.f) * w2v[n];
    }
    #pragma unroll
    for (int r = 0; r < 4; ++r) {
      ws[r] += __shfl_xor(ws[r], 1);
      ws[r] += __shfl_xor(ws[r], 2);
      ws[r] += __shfl_xor(ws[r], 4);
      ws[r] += __shfl_xor(ws[r], 8);
      ws[r] += b2v;
    }
    if (c15 == 0) {
      #pragma unroll
      for (int r = 0; r < 4; ++r) {
        const int trow = tt*16 + g*4 + r;
        if (trow < T_) sW1[trow] = ws[r];
      }
    }
  }
  __syncthreads();   // sW1 + sAcc-zero both complete

  // --- softmax phase A: per-k max & expsum ---
  for (int k = wave; k < KA; k += 4) {
    float m = -1e9f;
    for (int tt4 = 0; tt4 < 4; ++tt4) {
      int t = tt4*64 + lane;
      if (t < T_ && sAttr[t] == k) m = fmaxf(m, sW1[t]);
    }
    #pragma unroll
    for (int off = 32; off > 0; off >>= 1) m = fmaxf(m, __shfl_xor(m, off));
    float e = 0.f;
    for (int tt4 = 0; tt4 < 4; ++tt4) {
      int t = tt4*64 + lane;
      if (t < T_ && sAttr[t] == k) e += __expf(sW1[t] - m);
    }
    #pragma unroll
    for (int off = 32; off > 0; off >>= 1) e += __shfl_xor(e, off);
    if (lane == 0) { sM[k] = m; sE[k] = e; }
  }
  __syncthreads();
  if (tid < T_) {
    int k = sAttr[tid];
    float e = sE[k];
    sP[tid] = (e > 0.f) ? __expf(sW1[tid] - sM[k]) * __builtin_amdgcn_rcpf(e) : 0.f;
  }
  __syncthreads();

  // --- phase B: one gather pass, 1-deep prefetch -> cluster + ui1 ---
  float uiacc = 0.f;
  {
    float vcur = emb[(size_t)sIds[wave]*64 + lane];
    for (int t = wave; t < T_; t += 4) {
      const int tn = t + 4;
      float vnext = 0.f;
      if (tn < T_) vnext = emb[(size_t)sIds[tn]*64 + lane];
      const int k = sAttr[t];
      sAcc[wave][k][lane] += sP[t] * vcur;
      uiacc += sW1[t] * vcur;
      vcur = vnext;
    }
  }
  sUi[wave][lane] = uiacc;
  __syncthreads();

  for (int i = tid; i < KA*64; i += 256) {
    cluster_out[(size_t)b*(KA*64) + i] =
        sAcc[0][0][i] + sAcc[1][0][i] + sAcc[2][0][i] + sAcc[3][0][i];
  }
  if (tid < 64) {
    ui1_out[(size_t)b*64 + tid] =
        sUi[0][tid] + sUi[1][tid] + sUi[2][tid] + sUi[3][tid];
  }
}

// ============================================================
// K3 (MFMA): GRU, 16 rows/block, producer-consumer. (unchanged, passing)
// ============================================================
#define GRU_ROWS 16
__global__ __launch_bounds__(512) void k_gru(
    const int* __restrict__ hist_ids, const float* __restrict__ emb,
    const float* __restrict__ Wx, const float* __restrict__ Wh,
    const float* __restrict__ gb, float* __restrict__ hfin_out)
{
  __shared__ short sH[2][16*64];
  __shared__ short sX[4][16*64];
  __shared__ int   sIds[16*200];

  const int tid  = threadIdx.x;
  const int w    = tid >> 6;
  const int lane = tid & 63;
  const int g    = lane >> 4;
  const int c15  = lane & 15;
  const int b0   = blockIdx.x * GRU_ROWS;

  for (int i = tid; i < 16*200; i += 512) {
    const int r = i / 200, t = i - r*200;
    sIds[i] = hist_ids[(size_t)(b0 + r)*T_ + t];
  }
  for (int i = tid; i < 16*64; i += 512) sH[0][i] = 0;
  __syncthreads();

  if (w >= 4) {
    const int stane = (w - 4)*64 + lane;
    const int srow  = stane >> 4;
    const int scol  = (stane & 15) * 4;
    const int sidx  = srow*64 + (((scol >> 3) ^ (srow & 7))*8) + (scol & 7);
    const int* idrow = &sIds[srow*200];
    #pragma unroll
    for (int p = 0; p < 2; ++p) {
      const float4 f = *(const float4*)(emb + (size_t)idrow[p]*64 + scol);
      uint2 u; u.x = cvtpk(f.x, f.y); u.y = cvtpk(f.z, f.w);
      *(uint2*)&sX[p][sidx] = u;
    }
    __syncthreads();
    for (int t = 0; t < T_; ++t) {
      const int t2 = (t + 2 < T_) ? (t + 2) : (T_ - 1);
      const float4 f = *(const float4*)(emb + (size_t)idrow[t2]*64 + scol);
      uint2 u; u.x = cvtpk(f.x, f.y); u.y = cvtpk(f.z, f.w);
      *(uint2*)&sX[(t + 2) & 3][sidx] = u;
      __syncthreads();
    }
  } else {
    bf16x8 bx[3][2], bh[3][2];
    #pragma unroll
    for (int l = 0; l < 3; ++l) {
      const int jb = (l*4 + w)*16 + c15;
      #pragma unroll
      for (int kk = 0; kk < 2; ++kk) {
        bf16x8 vx, vh;
        #pragma unroll
        for (int e = 0; e < 8; ++e) {
          const int krow = kk*32 + g*8 + e;
          vx[e] = f2bf(Wx[(size_t)krow*192 + jb]);
          vh[e] = f2bf(Wh[(size_t)krow*192 + jb]);
        }
        bx[l][kk] = vx; bh[l][kk] = vh;
      }
    }
    float bias[3];
    #pragma unroll
    for (int l = 0; l < 3; ++l) bias[l] = gb[l*64 + w*16 + c15];

    const int rs = c15 & 7;
    const int ridx0 = c15*64 + ((g    ) ^ rs)*8;
    const int ridx1 = c15*64 + ((g + 4) ^ rs)*8;
    int widx[4];
    {
      const int unit = w*2 + (c15 >> 3);
      #pragma unroll
      for (int r = 0; r < 4; ++r) {
        const int row = g*4 + r;
        widx[r] = row*64 + ((unit ^ (row & 7))*8) + (c15 & 7);
      }
    }
    float hold[4] = {0.f, 0.f, 0.f, 0.f};
    __syncthreads();

    #pragma unroll 2
    for (int t = 0; t < T_; ++t) {
      const short* hbuf = sH[t & 1];
      short*       hnxt = sH[(t & 1) ^ 1];
      const short* xbuf = sX[t & 3];

      bf16x8 ax0 = *(const bf16x8*)&xbuf[ridx0];
      bf16x8 ax1 = *(const bf16x8*)&xbuf[ridx1];
      bf16x8 ah0 = *(const bf16x8*)&hbuf[ridx0];
      bf16x8 ah1 = *(const bf16x8*)&hbuf[ridx1];

      f32x4 aX[3], aH[3];
      #pragma unroll
      for (int l = 0; l < 3; ++l) {
        aX[l] = f32x4{bias[l], bias[l], bias[l], bias[l]};
        aH[l] = f32x4{0.f, 0.f, 0.f, 0.f};
      }
      #pragma unroll
      for (int l = 0; l < 3; ++l) {
        aH[l] = __builtin_amdgcn_mfma_f32_16x16x32_bf16(ah0, bh[l][0], aH[l], 0, 0, 0);
        aH[l] = __builtin_amdgcn_mfma_f32_16x16x32_bf16(ah1, bh[l][1], aH[l], 0, 0, 0);
        aX[l] = __builtin_amdgcn_mfma_f32_16x16x32_bf16(ax0, bx[l][0], aX[l], 0, 0, 0);
        aX[l] = __builtin_amdgcn_mfma_f32_16x16x32_bf16(ax1, bx[l][1], aX[l], 0, 0, 0);
      }

      #pragma unroll
      for (int r = 0; r < 4; ++r) {
        float z  = sigf(aX[0][r] + aH[0][r]);
        float rr = sigf(aX[1][r] + aH[1][r]);
        float nn = tanhfast(aX[2][r] + rr * aH[2][r]);
        hold[r] = nn + z * (hold[r] - nn);
        hnxt[widx[r]] = f2bf(hold[r]);
      }
      __syncthreads();
    }

    #pragma unroll
    for (int r = 0; r < 4; ++r)
      hfin_out[(size_t)(b0 + g*4 + r)*64 + w*16 + c15] = hold[r];
  }
}

// ============================================================
// K4 (MFMA): activation unit over 16 clusters -> ui_l2[b,64] (unchanged)
// ============================================================
__global__ __launch_bounds__(256) void k_act2(
    const int* __restrict__ item_id, const float* __restrict__ emb,
    const float* __restrict__ auW2, const float* __restrict__ aub2,
    const float* __restrict__ qp_in, const float* __restrict__ cluster_in,
    const short* __restrict__ bg_in, float* __restrict__ ui2_out)
{
  __shared__ short sB2[8192];
  __shared__ float sWs[4][16];
  __shared__ float sWf[16];
  __shared__ float sUi[4][64];

  const int b = blockIdx.x;
  const int tid = threadIdx.x;
  const int wave = tid >> 6, lane = tid & 63;
  const int g = lane >> 4;
  const int c15 = lane & 15;
  const int itrow = item_id[b];

  for (int i = tid; i < 4096; i += 256)
    ((unsigned*)sB2)[i] = ((const unsigned*)bg_in)[i];
  __syncthreads();

  const float4* itemp = (const float4*)(emb + (size_t)itrow*64);
  float4 q0 = itemp[g*2],     q1 = itemp[g*2 + 1];
  float4 q2 = itemp[8 + g*2], q3 = itemp[8 + g*2 + 1];
  const float4* kp = (const float4*)(cluster_in + (size_t)b*(KA*64) + c15*64);
  float4 k0 = kp[g*2],     k1 = kp[g*2 + 1];
  float4 k2 = kp[8 + g*2], k3 = kp[8 + g*2 + 1];
  bf16x8 a0 = pack8(k0, k1);
  bf16x8 a1 = pack8(k2, k3);
  bf16x8 a2 = pack8m(k0, k1, q0, q1);
  bf16x8 a3 = pack8m(k2, k3, q2, q3);

  const float qpv = qp_in[(size_t)b*64 + wave*16 + c15];
  const float w2v = auW2[wave*16 + c15];
  f32x4 acc = f32x4{qpv, qpv, qpv, qpv};
  acc = __builtin_amdgcn_mfma_f32_16x16x32_bf16(a0, *(const bf16x8*)&sB2[(0*4+g)*512 + (wave*16+c15)*8], acc, 0, 0, 0);
  acc = __builtin_amdgcn_mfma_f32_16x16x32_bf16(a1, *(const bf16x8*)&sB2[(1*4+g)*512 + (wave*16+c15)*8], acc, 0, 0, 0);
  acc = __builtin_amdgcn_mfma_f32_16x16x32_bf16(a2, *(const bf16x8*)&sB2[(2*4+g)*512 + (wave*16+c15)*8], acc, 0, 0, 0);
  acc = __builtin_amdgcn_mfma_f32_16x16x32_bf16(a3, *(const bf16x8*)&sB2[(3*4+g)*512 + (wave*16+c15)*8], acc, 0, 0, 0);

  float ws[4];
  #pragma unroll
  for (int r = 0; r < 4; ++r) {
    float v = fmaxf(acc[r], 0.f) * w2v;
    v += __shfl_xor(v, 1);
    v += __shfl_xor(v, 2);
    v += __shfl_xor(v, 4);
    v += __shfl_xor(v, 8);
    ws[r] = v;
  }
  if (c15 == 0) {
    #pragma unroll
    for (int r = 0; r < 4; ++r) sWs[wave][g*4 + r] = ws[r];
  }
  __syncthreads();
  if (tid < KA)
    sWf[tid] = sWs[0][tid] + sWs[1][tid] + sWs[2][tid] + sWs[3][tid] + aub2[0];
  __syncthreads();

  float uiacc = 0.f;
  #pragma unroll
  for (int kk = 0; kk < 4; ++kk) {
    const int k = wave*4 + kk;
    uiacc += sWf[k] * cluster_in[(size_t)b*(KA*64) + k*64 + lane];
  }
  sUi[wave][lane] = uiacc;
  __syncthreads();
  if (tid < 64) {
    ui2_out[(size_t)b*64 + tid] =
        sUi[0][tid] + sUi[1][tid] + sUi[2][tid] + sUi[3][tid];
  }
}

// ============================================================
// K5: final MLP (unchanged)
// ============================================================
#define MLP_ROWS 16
__global__ __launch_bounds__(256) void k_mlp(
    const int* __restrict__ item_id, const float* __restrict__ emb,
    const float* __restrict__ ui1, const float* __restrict__ ui2,
    const float* __restrict__ hfin,
    const float* __restrict__ W0, const float* __restrict__ b0,
    const float* __restrict__ W1, const float* __restrict__ b1,
    const float* __restrict__ fW, const float* __restrict__ fb,
    float* __restrict__ out)
{
  __shared__ float sC[MLP_ROWS][256];
  __shared__ float sX0[MLP_ROWS][256];
  __shared__ float sX1[MLP_ROWS][128];
  const int tid = threadIdx.x;
  const int rb  = blockIdx.x * MLP_ROWS;

  for (int idx = tid; idx < MLP_ROWS*256; idx += 256) {
    int r = idx >> 8, c = idx & 255;
    size_t row = (size_t)(rb + r);
    float v;
    if (c < 64)       v = ui1[row*64 + c];
    else if (c < 128) v = ui2[row*64 + (c-64)];
    else if (c < 192) v = hfin[row*64 + (c-128)];
    else              v = emb[(size_t)item_id[row]*64 + (c-192)];
    sC[r][c] = v;
  }
  __syncthreads();
  {
    float acc[MLP_ROWS];
    #pragma unroll
    for (int r = 0; r < MLP_ROWS; ++r) acc[r] = b0[tid];
    #pragma unroll 4
    for (int i = 0; i < 256; ++i) {
      float w = W0[(size_t)i*256 + tid];
      #pragma unroll
      for (int r = 0; r < MLP_ROWS; ++r) acc[r] += sC[r][i] * w;
    }
    #pragma unroll
    for (int r = 0; r < MLP_ROWS; ++r) sX0[r][tid] = fmaxf(acc[r], 0.f);
  }
  __syncthreads();
  if (tid < 128) {
    float acc[MLP_ROWS];
    #pragma unroll
    for (int r = 0; r < MLP_ROWS; ++r) acc[r] = b1[tid];
    #pragma unroll 4
    for (int i = 0; i < 256; ++i) {
      float w = W1[(size_t)i*128 + tid];
      #pragma unroll
      for (int r = 0; r < MLP_ROWS; ++r) acc[r] += sX0[r][i] * w;
    }
    #pragma unroll
    for (int r = 0; r < MLP_ROWS; ++r) sX1[r][tid] = fmaxf(acc[r], 0.f);
  }
  __syncthreads();
  {
    int r = tid >> 4, l16 = tid & 15;
    float p = 0.f;
    for (int i = l16; i < 128; i += 16) p += sX1[r][i] * fW[i];
    #pragma unroll
    for (int off = 8; off > 0; off >>= 1) p += __shfl_xor(p, off);
    if (l16 == 0) {
      float logit = p + fb[0];
      out[rb + r] = sigmoidf_(logit);
    }
  }
}

// ============================================================
extern "C" void kernel_launch(void* const* d_in, const int* in_sizes, int n_in,
                              void* d_out, int out_size, void* d_ws, size_t ws_size,
                              hipStream_t stream)
{
  const int*   item_id  = (const int*)d_in[0];
  const int*   hist_ids = (const int*)d_in[1];
  const int*   attrs    = (const int*)d_in[2];
  const float* emb      = (const float*)d_in[3];
  const float* auW1     = (const float*)d_in[4];
  const float* aub1     = (const float*)d_in[5];
  const float* auW2     = (const float*)d_in[6];
  const float* aub2     = (const float*)d_in[7];
  const float* gWx      = (const float*)d_in[8];
  const float* gWh      = (const float*)d_in[9];
  const float* gb       = (const float*)d_in[10];
  const float* W0       = (const float*)d_in[11];
  const float* b0       = (const float*)d_in[12];
  const float* W1       = (const float*)d_in[13];
  const float* b1       = (const float*)d_in[14];
  const float* fW       = (const float*)d_in[15];
  const float* fb       = (const float*)d_in[16];

  float* out = (float*)d_out;
  float* ws  = (float*)d_ws;
  short* bg      = (short*)(ws + OFF_BG);
  float* wq      = ws + OFF_WQ;
  float* qp      = ws + OFF_QP;
  float* ui1     = ws + OFF_UI1;
  float* ui2     = ws + OFF_UI2;
  float* hfin    = ws + OFF_HF;
  float* cluster = ws + OFF_CL;

  k_prep<<<48, 256, 0, stream>>>(auW1, bg, wq);
  k_act1<<<B_, 256, 0, stream>>>(item_id, hist_ids, attrs, emb, aub1,
                                 auW2, aub2, bg, wq, qp, ui1, cluster);
  k_gru<<<B_/GRU_ROWS, 512, 0, stream>>>(hist_ids, emb, gWx, gWh, gb, hfin);
  k_act2<<<B_, 256, 0, stream>>>(item_id, emb, auW2, aub2, qp, cluster, bg,
                                 ui2);
  k_mlp<<<B_/MLP_ROWS, 256, 0, stream>>>(item_id, emb, ui1, ui2, hfin,
                                         W0, b0, W1, b1, fW, fb, out);
}